// Round 6
// baseline (2800.802 us; speedup 1.0000x reference)
//
#include <hip/hip_runtime.h>
#include <math.h>

// out = gelu( BN(segment_sum(H[src]*w, dst)) @ W + b ), exact gelu.
// N=100000, E=3200000, D=HIDDEN=128, all f32.
//
// Round-6: bucket-append (L2-resident tail lines) + LDS-accumulate pull.
//   K0: memset gcnt = 0
//   K1: convert H -> bf16 (RNE)                       [tier A]
//   K2: hist_bkg  gcnt[(dst>>6)*8 + (bid&7)]++
//   K3: scan1/scan2/scan3g -> gbase (immutable), gcur (cursor copy)
//   K4: append    payload[pos] = {src | dstlocal<<17, w}  (8B store; active
//                 tail-line span = 12.5K*64B ~ 800KB, L2-resident)
//   K5: pull_lds  block per 64-node bucket: stream payload, gather H rows
//                 8-deep, atomicAdd into LDS hl[64][128], write h dense
//   K6: fused BN + (h @ W) + bias + exact GELU, in place on d_out
// Fallback: push-based atomic scatter if ws too small.

#define DF 128
#define SCAN_ELEMS 1024
#define BKSH 6                 // 64 nodes per bucket
#define BKNODES (1 << BKSH)
#define NG 8                   // sub-cursors per bucket (XCD-proxy via bid&7)

// ---------------- Tier C fallback ----------------
__global__ __launch_bounds__(256) void scatter_kernel(
    const float* __restrict__ H, const int* __restrict__ esrc,
    const int* __restrict__ edst, const float* __restrict__ ew,
    float* __restrict__ h, int E) {
  int tid = blockIdx.x * blockDim.x + threadIdx.x;
  int e = tid >> 5;
  int lane = tid & 31;
  if (e >= E) return;
  int s = esrc[e];
  int d = edst[e];
  float w = ew[e];
  const float4* Hs = reinterpret_cast<const float4*>(H + (size_t)s * DF);
  float4 v = Hs[lane];
  float* hd = h + (size_t)d * DF + lane * 4;
  atomicAdd(hd + 0, v.x * w);
  atomicAdd(hd + 1, v.y * w);
  atomicAdd(hd + 2, v.z * w);
  atomicAdd(hd + 3, v.w * w);
}

// ---------------- H -> bf16 (RNE) ----------------
__global__ __launch_bounds__(256) void convert_bf16_kernel(
    const float4* __restrict__ H4, ushort4* __restrict__ Hb, int n4) {
  int i = blockIdx.x * blockDim.x + threadIdx.x;
  if (i >= n4) return;
  float4 v = H4[i];
  auto cvt = [](float f) -> unsigned short {
    unsigned u = __float_as_uint(f);
    unsigned r = (u + 0x7FFFu + ((u >> 16) & 1u)) >> 16;
    return (unsigned short)r;
  };
  ushort4 o;
  o.x = cvt(v.x); o.y = cvt(v.y); o.z = cvt(v.z); o.w = cvt(v.w);
  Hb[i] = o;
}

// ---------------- bucket histogram ----------------
__global__ __launch_bounds__(256) void hist_bkg_kernel(
    const int* __restrict__ edst, int* __restrict__ gcnt, int E) {
  int e = blockIdx.x * blockDim.x + threadIdx.x;
  if (e >= E) return;
  int bk = edst[e] >> BKSH;
  int g = blockIdx.x & (NG - 1);
  atomicAdd(&gcnt[bk * NG + g], 1);
}

// ---------------- scans (over NBKG = nbk*NG elements) ----------------
__global__ __launch_bounds__(256) void scan1_kernel(
    const int* __restrict__ cnt, int* __restrict__ pre,
    int* __restrict__ bsum, int N) {
  __shared__ int s[256];
  int t = threadIdx.x;
  int base = blockIdx.x * SCAN_ELEMS + t * 4;
  int v0 = (base + 0 < N) ? cnt[base + 0] : 0;
  int v1 = (base + 1 < N) ? cnt[base + 1] : 0;
  int v2 = (base + 2 < N) ? cnt[base + 2] : 0;
  int v3 = (base + 3 < N) ? cnt[base + 3] : 0;
  int tsum = v0 + v1 + v2 + v3;
  s[t] = tsum;
  __syncthreads();
  for (int off = 1; off < 256; off <<= 1) {
    int tmp = (t >= off) ? s[t - off] : 0;
    __syncthreads();
    s[t] += tmp;
    __syncthreads();
  }
  int run = s[t] - tsum;
  if (base + 0 < N) pre[base + 0] = run;
  run += v0;
  if (base + 1 < N) pre[base + 1] = run;
  run += v1;
  if (base + 2 < N) pre[base + 2] = run;
  run += v2;
  if (base + 3 < N) pre[base + 3] = run;
  if (t == 255) bsum[blockIdx.x] = s[255];
}

__global__ __launch_bounds__(128) void scan2_kernel(int* __restrict__ bsum, int nb) {
  __shared__ int s[128];
  int t = threadIdx.x;
  int v = (t < nb) ? bsum[t] : 0;
  s[t] = v;
  __syncthreads();
  for (int off = 1; off < 128; off <<= 1) {
    int tmp = (t >= off) ? s[t - off] : 0;
    __syncthreads();
    s[t] += tmp;
    __syncthreads();
  }
  if (t < nb) bsum[t] = s[t] - v;
  if (t == 127) bsum[nb] = s[127];
}

__global__ __launch_bounds__(256) void scan3g_kernel(
    int* __restrict__ gbase, const int* __restrict__ bsum,
    int* __restrict__ gcur, int NBKG, int nb) {
  int i = blockIdx.x * blockDim.x + threadIdx.x;
  if (i < NBKG) {
    int v = gbase[i] + bsum[i >> 10];
    gbase[i] = v;
    gcur[i] = v;
  }
  if (i == 0) gbase[NBKG] = bsum[nb];
}

// ---------------- bucket append: one 8B store per edge ----------------
__global__ __launch_bounds__(256) void append_kernel(
    const int* __restrict__ esrc, const int* __restrict__ edst,
    const float* __restrict__ ew, int* __restrict__ gcur,
    uint2* __restrict__ payload, int E) {
  int e = blockIdx.x * blockDim.x + threadIdx.x;
  if (e >= E) return;
  int d = edst[e];
  int bk = d >> BKSH;
  int dl = d & (BKNODES - 1);
  int g = blockIdx.x & (NG - 1);
  int pos = atomicAdd(&gcur[bk * NG + g], 1);
  uint2 v;
  v.x = (unsigned)esrc[e] | ((unsigned)dl << 17);
  v.y = __float_as_uint(ew[e]);
  payload[pos] = v;
}

// ---------------- pull: block per bucket, LDS accumulate ----------------
template <int BF16>
__global__ __launch_bounds__(256) void pull_lds_kernel(
    const void* __restrict__ Hv, const int* __restrict__ gbase,
    const uint2* __restrict__ payload, float* __restrict__ h, int N) {
  __shared__ float hl[BKNODES][DF];  // 32 KB
  int t = threadIdx.x;
  int bk = blockIdx.x;
  int wid = t >> 6;
  int lane = t & 63;
  const unsigned* __restrict__ Hb = (const unsigned*)Hv;  // 64 u32 / row
  const float2* __restrict__ H2 = (const float2*)Hv;      // 64 f2  / row

  for (int i = t; i < BKNODES * DF; i += 256)
    reinterpret_cast<float*>(hl)[i] = 0.0f;
  __syncthreads();

  int rs = gbase[bk * NG];
  int re = gbase[bk * NG + NG];

  // Waves take 8 contiguous edges at a time, stride 32 (4 waves).
  for (int j0 = rs + wid * 8; j0 < re; j0 += 32) {
    int cnt = re - j0;
    if (cnt >= 8) {
      uint2 m[8];
#pragma unroll
      for (int k = 0; k < 8; ++k) m[k] = payload[j0 + k];
      float lo[8], hi[8];
#pragma unroll
      for (int k = 0; k < 8; ++k) {
        unsigned src = m[k].x & 0x1FFFFu;
        if (BF16) {
          unsigned p = Hb[(size_t)src * 64 + lane];
          lo[k] = __uint_as_float(p << 16);
          hi[k] = __uint_as_float(p & 0xFFFF0000u);
        } else {
          float2 u = H2[(size_t)src * 64 + lane];
          lo[k] = u.x;
          hi[k] = u.y;
        }
      }
#pragma unroll
      for (int k = 0; k < 8; ++k) {
        float w = __uint_as_float(m[k].y);
        int dl = (int)(m[k].x >> 17);
        atomicAdd(&hl[dl][2 * lane + 0], lo[k] * w);
        atomicAdd(&hl[dl][2 * lane + 1], hi[k] * w);
      }
    } else {
      for (int j = j0; j < re; ++j) {
        uint2 m = payload[j];
        unsigned src = m.x & 0x1FFFFu;
        float w = __uint_as_float(m.y);
        int dl = (int)(m.x >> 17);
        float lo, hi;
        if (BF16) {
          unsigned p = Hb[(size_t)src * 64 + lane];
          lo = __uint_as_float(p << 16);
          hi = __uint_as_float(p & 0xFFFF0000u);
        } else {
          float2 u = H2[(size_t)src * 64 + lane];
          lo = u.x;
          hi = u.y;
        }
        atomicAdd(&hl[dl][2 * lane + 0], lo * w);
        atomicAdd(&hl[dl][2 * lane + 1], hi * w);
      }
    }
  }
  __syncthreads();

  int node0 = bk << BKSH;
  for (int i = t; i < BKNODES * DF; i += 256) {
    int r = i >> 7;
    int c = i & (DF - 1);
    int node = node0 + r;
    if (node < N) h[(size_t)node * DF + c] = hl[r][c];
  }
}

// ---------------- fused BN + GEMM + GELU (verified rounds 1-5) ----------------
__global__ __launch_bounds__(256) void fused_bn_gemm_gelu(
    float* __restrict__ hout, const float* __restrict__ gamma,
    const float* __restrict__ beta, const float* __restrict__ mean,
    const float* __restrict__ var, const float* __restrict__ W,
    const float* __restrict__ b, int N) {
  __shared__ float s_s[DF];
  __shared__ float s_t[DF];
  __shared__ float s_hb[16][DF];
  __shared__ float s_W[32][DF];

  int t = threadIdx.x;
  if (t < DF) {
    float sv = gamma[t] * rsqrtf(var[t] + 1e-3f);
    s_s[t] = sv;
    s_t[t] = beta[t] - mean[t] * sv;
  }
  __syncthreads();

  int n0 = blockIdx.x * 16;
  for (int i = t; i < 16 * DF; i += 256) {
    int r = i >> 7;
    int c = i & (DF - 1);
    int node = n0 + r;
    float hv = (node < N) ? hout[(size_t)node * DF + c] : 0.0f;
    s_hb[r][c] = hv * s_s[c] + s_t[c];
  }

  float acc[8];
#pragma unroll
  for (int i = 0; i < 8; i++) acc[i] = 0.0f;

  int col = t & (DF - 1);
  int half = t >> 7;

  for (int kc = 0; kc < DF; kc += 32) {
    __syncthreads();
    for (int i = t; i < 32 * DF; i += 256) {
      int r = i >> 7;
      int c = i & (DF - 1);
      s_W[r][c] = W[(size_t)(kc + r) * DF + c];
    }
    __syncthreads();
#pragma unroll
    for (int kk = 0; kk < 32; kk++) {
      float wv = s_W[kk][col];
#pragma unroll
      for (int i = 0; i < 8; i++) {
        acc[i] += s_hb[half + i * 2][kc + kk] * wv;
      }
    }
  }

  float bb = b[col];
#pragma unroll
  for (int i = 0; i < 8; i++) {
    int node = n0 + half + i * 2;
    if (node < N) {
      float x = acc[i] + bb;
      float g = 0.5f * x * (1.0f + erff(x * 0.70710678118654752440f));
      hout[(size_t)node * DF + col] = g;
    }
  }
}

extern "C" void kernel_launch(void* const* d_in, const int* in_sizes, int n_in,
                              void* d_out, int out_size, void* d_ws, size_t ws_size,
                              hipStream_t stream) {
  const float* H     = (const float*)d_in[0];
  const int*   esrc  = (const int*)d_in[1];
  const int*   edst  = (const int*)d_in[2];
  const float* ew    = (const float*)d_in[3];
  const float* gamma = (const float*)d_in[4];
  const float* beta  = (const float*)d_in[5];
  const float* mean  = (const float*)d_in[6];
  const float* var   = (const float*)d_in[7];
  const float* W     = (const float*)d_in[8];
  const float* b     = (const float*)d_in[9];

  int N = in_sizes[0] / DF;
  int E = in_sizes[1];
  float* h = (float*)d_out;

  int nbk = (N + BKNODES - 1) / BKNODES;       // buckets
  int NBKG = nbk * NG;                          // sub-cursor count
  int nb2 = (NBKG + SCAN_ELEMS - 1) / SCAN_ELEMS;

  size_t off = 0;
  auto alloc = [&](size_t bytes) {
    size_t o = off;
    off += (bytes + 255) & ~(size_t)255;
    return o;
  };
  size_t o_gcnt  = alloc((size_t)NBKG * 4);     // also reused as nothing else
  size_t o_gbase = alloc((size_t)(NBKG + 1) * 4);
  size_t o_gcur  = alloc((size_t)NBKG * 4);
  size_t o_bsum  = alloc((size_t)(nb2 + 1) * 4);
  size_t o_pl    = alloc((size_t)E * 8);
  size_t need_bin = off;                        // tier B requirement
  size_t o_hb    = alloc((size_t)N * DF * 2);
  size_t need_bf16 = off;                       // tier A requirement

  char* ws = (char*)d_ws;

  if (ws_size >= need_bin) {
    int* gcnt   = (int*)(ws + o_gcnt);
    int* gbase  = (int*)(ws + o_gbase);
    int* gcur   = (int*)(ws + o_gcur);
    int* bsum   = (int*)(ws + o_bsum);
    uint2* payload = (uint2*)(ws + o_pl);
    bool tierA = (ws_size >= need_bf16);

    hipMemsetAsync(gcnt, 0, (size_t)NBKG * 4, stream);
    if (tierA) {
      ushort4* Hb = (ushort4*)(ws + o_hb);
      int n4 = N * DF / 4;
      convert_bf16_kernel<<<(n4 + 255) / 256, 256, 0, stream>>>(
          (const float4*)H, Hb, n4);
      hist_bkg_kernel<<<(E + 255) / 256, 256, 0, stream>>>(edst, gcnt, E);
      scan1_kernel<<<nb2, 256, 0, stream>>>(gcnt, gbase, bsum, NBKG);
      scan2_kernel<<<1, 128, 0, stream>>>(bsum, nb2);
      scan3g_kernel<<<(NBKG + 255) / 256, 256, 0, stream>>>(gbase, bsum, gcur,
                                                            NBKG, nb2);
      append_kernel<<<(E + 255) / 256, 256, 0, stream>>>(esrc, edst, ew, gcur,
                                                         payload, E);
      pull_lds_kernel<1><<<nbk, 256, 0, stream>>>((const void*)Hb, gbase,
                                                  payload, h, N);
    } else {
      hist_bkg_kernel<<<(E + 255) / 256, 256, 0, stream>>>(edst, gcnt, E);
      scan1_kernel<<<nb2, 256, 0, stream>>>(gcnt, gbase, bsum, NBKG);
      scan2_kernel<<<1, 128, 0, stream>>>(bsum, nb2);
      scan3g_kernel<<<(NBKG + 255) / 256, 256, 0, stream>>>(gbase, bsum, gcur,
                                                            NBKG, nb2);
      append_kernel<<<(E + 255) / 256, 256, 0, stream>>>(esrc, edst, ew, gcur,
                                                         payload, E);
      pull_lds_kernel<0><<<nbk, 256, 0, stream>>>((const void*)H, gbase,
                                                  payload, h, N);
    }
  } else {
    hipMemsetAsync(d_out, 0, (size_t)out_size * sizeof(float), stream);
    long long threads = (long long)E * 32;
    long long grid = (threads + 255) / 256;
    scatter_kernel<<<(int)grid, 256, 0, stream>>>(H, esrc, edst, ew, h, E);
  }

  fused_bn_gemm_gelu<<<(N + 15) / 16, 256, 0, stream>>>(h, gamma, beta, mean,
                                                        var, W, b, N);
}

// Round 7
// 734.418 us; speedup vs baseline: 3.8136x; 3.8136x over previous
//
#include <hip/hip_runtime.h>
#include <math.h>

// out = gelu( BN(segment_sum(H[src]*w, dst)) @ W + b ), exact gelu.
// N=100000, E=3200000, D=HIDDEN=128, all f32.
//
// Round-7: two-phase CSR build (bucket append -> bucket-local reorder),
//          keeping round-5's proven high-TLP pull_csr.
//   K0: memset cnt, gcnt
//   K1: convert H -> bf16 (RNE)
//   K2: hist2    cnt[dst]++  AND  gcnt[(dst>>6)*8 + (bid&7)]++
//   K3: scans    -> rowptr (per-node), gbase/gcur (per-bucket-group)
//                invariant: rowptr[bk*64] == gbase[bk*NG]
//   K4: append   payload[pos]={src|dl<<17,w}; tail lines ~800KB L2-resident
//   K5: reorder  block/bucket: 64 LDS cursors; payload seg -> exact CSR slots
//                (reads+writes confined to the bucket's own 16KB window)
//   K6: pull_csr wave/node, 8 independent bf16 row gathers in flight
//   K7: fused BN + (h @ W) + bias + exact GELU, in place on d_out
// Fallback: push-based atomic scatter if ws too small.

#define DF 128
#define SCAN_ELEMS 1024
#define BKSH 6
#define BKNODES (1 << BKSH)
#define NG 8

// ---------------- Tier C fallback ----------------
__global__ __launch_bounds__(256) void scatter_kernel(
    const float* __restrict__ H, const int* __restrict__ esrc,
    const int* __restrict__ edst, const float* __restrict__ ew,
    float* __restrict__ h, int E) {
  int tid = blockIdx.x * blockDim.x + threadIdx.x;
  int e = tid >> 5;
  int lane = tid & 31;
  if (e >= E) return;
  int s = esrc[e];
  int d = edst[e];
  float w = ew[e];
  const float4* Hs = reinterpret_cast<const float4*>(H + (size_t)s * DF);
  float4 v = Hs[lane];
  float* hd = h + (size_t)d * DF + lane * 4;
  atomicAdd(hd + 0, v.x * w);
  atomicAdd(hd + 1, v.y * w);
  atomicAdd(hd + 2, v.z * w);
  atomicAdd(hd + 3, v.w * w);
}

// ---------------- H -> bf16 (RNE) ----------------
__global__ __launch_bounds__(256) void convert_bf16_kernel(
    const float4* __restrict__ H4, ushort4* __restrict__ Hb, int n4) {
  int i = blockIdx.x * blockDim.x + threadIdx.x;
  if (i >= n4) return;
  float4 v = H4[i];
  auto cvt = [](float f) -> unsigned short {
    unsigned u = __float_as_uint(f);
    unsigned r = (u + 0x7FFFu + ((u >> 16) & 1u)) >> 16;
    return (unsigned short)r;
  };
  ushort4 o;
  o.x = cvt(v.x); o.y = cvt(v.y); o.z = cvt(v.z); o.w = cvt(v.w);
  Hb[i] = o;
}

// ---------------- fused histogram: per-node AND per-(bucket,group) ----------
__global__ __launch_bounds__(256) void hist2_kernel(
    const int* __restrict__ edst, int* __restrict__ cnt,
    int* __restrict__ gcnt, int E) {
  int e = blockIdx.x * blockDim.x + threadIdx.x;
  if (e >= E) return;
  int d = edst[e];
  atomicAdd(&cnt[d], 1);
  int bk = d >> BKSH;
  int g = blockIdx.x & (NG - 1);
  atomicAdd(&gcnt[bk * NG + g], 1);
}

// ---------------- scans ----------------
__global__ __launch_bounds__(256) void scan1_kernel(
    const int* __restrict__ cnt, int* __restrict__ pre,
    int* __restrict__ bsum, int N) {
  __shared__ int s[256];
  int t = threadIdx.x;
  int base = blockIdx.x * SCAN_ELEMS + t * 4;
  int v0 = (base + 0 < N) ? cnt[base + 0] : 0;
  int v1 = (base + 1 < N) ? cnt[base + 1] : 0;
  int v2 = (base + 2 < N) ? cnt[base + 2] : 0;
  int v3 = (base + 3 < N) ? cnt[base + 3] : 0;
  int tsum = v0 + v1 + v2 + v3;
  s[t] = tsum;
  __syncthreads();
  for (int off = 1; off < 256; off <<= 1) {
    int tmp = (t >= off) ? s[t - off] : 0;
    __syncthreads();
    s[t] += tmp;
    __syncthreads();
  }
  int run = s[t] - tsum;
  if (base + 0 < N) pre[base + 0] = run;
  run += v0;
  if (base + 1 < N) pre[base + 1] = run;
  run += v1;
  if (base + 2 < N) pre[base + 2] = run;
  run += v2;
  if (base + 3 < N) pre[base + 3] = run;
  if (t == 255) bsum[blockIdx.x] = s[255];
}

__global__ __launch_bounds__(128) void scan2_kernel(int* __restrict__ bsum, int nb) {
  __shared__ int s[128];
  int t = threadIdx.x;
  int v = (t < nb) ? bsum[t] : 0;
  s[t] = v;
  __syncthreads();
  for (int off = 1; off < 128; off <<= 1) {
    int tmp = (t >= off) ? s[t - off] : 0;
    __syncthreads();
    s[t] += tmp;
    __syncthreads();
  }
  if (t < nb) bsum[t] = s[t] - v;
  if (t == 127) bsum[nb] = s[127];
}

// finalize per-bucket-group bases + cursor copy
__global__ __launch_bounds__(256) void scan3g_kernel(
    int* __restrict__ gbase, const int* __restrict__ bsum,
    int* __restrict__ gcur, int NBKG, int nb) {
  int i = blockIdx.x * blockDim.x + threadIdx.x;
  if (i < NBKG) {
    int v = gbase[i] + bsum[i >> 10];
    gbase[i] = v;
    gcur[i] = v;
  }
  if (i == 0) gbase[NBKG] = bsum[nb];
}

// finalize per-node rowptr (no cursor needed; reorder uses LDS cursors)
__global__ __launch_bounds__(256) void scan3n_kernel(
    int* __restrict__ rowptr, const int* __restrict__ bsum, int N, int nb) {
  int i = blockIdx.x * blockDim.x + threadIdx.x;
  if (i < N) rowptr[i] = rowptr[i] + bsum[i >> 10];
  if (i == 0) rowptr[N] = bsum[nb];
}

// ---------------- bucket append: one 8B store per edge ----------------
__global__ __launch_bounds__(256) void append_kernel(
    const int* __restrict__ esrc, const int* __restrict__ edst,
    const float* __restrict__ ew, int* __restrict__ gcur,
    uint2* __restrict__ payload, int E) {
  int e = blockIdx.x * blockDim.x + threadIdx.x;
  if (e >= E) return;
  int d = edst[e];
  int bk = d >> BKSH;
  int dl = d & (BKNODES - 1);
  int g = blockIdx.x & (NG - 1);
  int pos = atomicAdd(&gcur[bk * NG + g], 1);
  uint2 v;
  v.x = (unsigned)esrc[e] | ((unsigned)dl << 17);
  v.y = __float_as_uint(ew[e]);
  payload[pos] = v;
}

// ---------------- bucket-local reorder into exact per-node CSR -------------
__global__ __launch_bounds__(256) void reorder_kernel(
    const uint2* __restrict__ payload, const int* __restrict__ gbase,
    const int* __restrict__ rowptr, uint2* __restrict__ csr, int N) {
  __shared__ int cur[BKNODES];
  int t = threadIdx.x;
  int bk = blockIdx.x;
  int node0 = bk << BKSH;
  if (t < BKNODES) {
    int node = node0 + t;
    cur[t] = (node < N) ? rowptr[node] : 0;
  }
  __syncthreads();
  int rs = gbase[bk * NG];
  int re = gbase[bk * NG + NG];
  for (int j = rs + t; j < re; j += 256) {
    uint2 m = payload[j];
    int dl = (int)(m.x >> 17);
    int pos = atomicAdd(&cur[dl], 1);
    uint2 o;
    o.x = m.x & 0x1FFFFu;
    o.y = m.y;
    csr[pos] = o;  // within [rs,re): 16KB window, L2-resident
  }
}

// ---------------- CSR pull (round-5 verified): wave per node ----------------
template <int BF16>
__global__ __launch_bounds__(256) void pull_csr_kernel(
    const void* __restrict__ Hv, const int* __restrict__ rowptr,
    const uint2* __restrict__ csr_sw, float* __restrict__ h, int N) {
  int wave = threadIdx.x >> 6;
  int lane = threadIdx.x & 63;
  int node = blockIdx.x * 4 + wave;
  if (node >= N) return;
  const unsigned* __restrict__ Hb = (const unsigned*)Hv;
  const float2* __restrict__ H2 = (const float2*)Hv;

  int rs = rowptr[node];
  int re = rowptr[node + 1];
  float ax = 0.0f, ay = 0.0f;

  int j = rs;
  for (; j + 8 <= re; j += 8) {
    uint2 m[8];
#pragma unroll
    for (int k = 0; k < 8; ++k) m[k] = csr_sw[j + k];
    float lo[8], hi[8];
#pragma unroll
    for (int k = 0; k < 8; ++k) {
      if (BF16) {
        unsigned p = Hb[(size_t)m[k].x * 64 + lane];
        lo[k] = __uint_as_float(p << 16);
        hi[k] = __uint_as_float(p & 0xFFFF0000u);
      } else {
        float2 u = H2[(size_t)m[k].x * 64 + lane];
        lo[k] = u.x;
        hi[k] = u.y;
      }
    }
#pragma unroll
    for (int k = 0; k < 8; ++k) {
      float w = __uint_as_float(m[k].y);
      ax = fmaf(lo[k], w, ax);
      ay = fmaf(hi[k], w, ay);
    }
  }
  for (; j < re; ++j) {
    uint2 m = csr_sw[j];
    float w = __uint_as_float(m.y);
    if (BF16) {
      unsigned p = Hb[(size_t)m.x * 64 + lane];
      ax = fmaf(__uint_as_float(p << 16), w, ax);
      ay = fmaf(__uint_as_float(p & 0xFFFF0000u), w, ay);
    } else {
      float2 u = H2[(size_t)m.x * 64 + lane];
      ax = fmaf(u.x, w, ax);
      ay = fmaf(u.y, w, ay);
    }
  }

  float2 r;
  r.x = ax;
  r.y = ay;
  reinterpret_cast<float2*>(h)[(size_t)node * 64 + lane] = r;
}

// ---------------- fused BN + GEMM + GELU (verified rounds 1-6) --------------
__global__ __launch_bounds__(256) void fused_bn_gemm_gelu(
    float* __restrict__ hout, const float* __restrict__ gamma,
    const float* __restrict__ beta, const float* __restrict__ mean,
    const float* __restrict__ var, const float* __restrict__ W,
    const float* __restrict__ b, int N) {
  __shared__ float s_s[DF];
  __shared__ float s_t[DF];
  __shared__ float s_hb[16][DF];
  __shared__ float s_W[32][DF];

  int t = threadIdx.x;
  if (t < DF) {
    float sv = gamma[t] * rsqrtf(var[t] + 1e-3f);
    s_s[t] = sv;
    s_t[t] = beta[t] - mean[t] * sv;
  }
  __syncthreads();

  int n0 = blockIdx.x * 16;
  for (int i = t; i < 16 * DF; i += 256) {
    int r = i >> 7;
    int c = i & (DF - 1);
    int node = n0 + r;
    float hv = (node < N) ? hout[(size_t)node * DF + c] : 0.0f;
    s_hb[r][c] = hv * s_s[c] + s_t[c];
  }

  float acc[8];
#pragma unroll
  for (int i = 0; i < 8; i++) acc[i] = 0.0f;

  int col = t & (DF - 1);
  int half = t >> 7;

  for (int kc = 0; kc < DF; kc += 32) {
    __syncthreads();
    for (int i = t; i < 32 * DF; i += 256) {
      int r = i >> 7;
      int c = i & (DF - 1);
      s_W[r][c] = W[(size_t)(kc + r) * DF + c];
    }
    __syncthreads();
#pragma unroll
    for (int kk = 0; kk < 32; kk++) {
      float wv = s_W[kk][col];
#pragma unroll
      for (int i = 0; i < 8; i++) {
        acc[i] += s_hb[half + i * 2][kc + kk] * wv;
      }
    }
  }

  float bb = b[col];
#pragma unroll
  for (int i = 0; i < 8; i++) {
    int node = n0 + half + i * 2;
    if (node < N) {
      float x = acc[i] + bb;
      float g = 0.5f * x * (1.0f + erff(x * 0.70710678118654752440f));
      hout[(size_t)node * DF + col] = g;
    }
  }
}

extern "C" void kernel_launch(void* const* d_in, const int* in_sizes, int n_in,
                              void* d_out, int out_size, void* d_ws, size_t ws_size,
                              hipStream_t stream) {
  const float* H     = (const float*)d_in[0];
  const int*   esrc  = (const int*)d_in[1];
  const int*   edst  = (const int*)d_in[2];
  const float* ew    = (const float*)d_in[3];
  const float* gamma = (const float*)d_in[4];
  const float* beta  = (const float*)d_in[5];
  const float* mean  = (const float*)d_in[6];
  const float* var   = (const float*)d_in[7];
  const float* W     = (const float*)d_in[8];
  const float* b     = (const float*)d_in[9];

  int N = in_sizes[0] / DF;
  int E = in_sizes[1];
  float* h = (float*)d_out;

  int nbk = (N + BKNODES - 1) / BKNODES;
  int NBKG = nbk * NG;
  int nbA = (NBKG + SCAN_ELEMS - 1) / SCAN_ELEMS;  // bucket-group scan blocks
  int nbB = (N + SCAN_ELEMS - 1) / SCAN_ELEMS;     // per-node scan blocks

  size_t off = 0;
  auto alloc = [&](size_t bytes) {
    size_t o = off;
    off += (bytes + 255) & ~(size_t)255;
    return o;
  };
  size_t o_cnt    = alloc((size_t)N * 4);
  size_t o_rowptr = alloc((size_t)(N + 1) * 4);
  size_t o_gcnt   = alloc((size_t)NBKG * 4);
  size_t o_gbase  = alloc((size_t)(NBKG + 1) * 4);
  size_t o_gcur   = alloc((size_t)NBKG * 4);
  size_t o_bsumA  = alloc((size_t)(nbA + 1) * 4);
  size_t o_bsumB  = alloc((size_t)(nbB + 1) * 4);
  size_t o_pl     = alloc((size_t)E * 8);
  size_t o_csr    = alloc((size_t)E * 8);
  size_t need_bin = off;
  size_t o_hb     = alloc((size_t)N * DF * 2);
  size_t need_bf16 = off;

  char* ws = (char*)d_ws;

  if (ws_size >= need_bin) {
    int* cnt     = (int*)(ws + o_cnt);
    int* rowptr  = (int*)(ws + o_rowptr);
    int* gcnt    = (int*)(ws + o_gcnt);
    int* gbase   = (int*)(ws + o_gbase);
    int* gcur    = (int*)(ws + o_gcur);
    int* bsumA   = (int*)(ws + o_bsumA);
    int* bsumB   = (int*)(ws + o_bsumB);
    uint2* payload = (uint2*)(ws + o_pl);
    uint2* csr     = (uint2*)(ws + o_csr);
    bool tierA = (ws_size >= need_bf16);

    hipMemsetAsync(cnt, 0, (size_t)N * 4, stream);
    hipMemsetAsync(gcnt, 0, (size_t)NBKG * 4, stream);

    if (tierA) {
      ushort4* Hb = (ushort4*)(ws + o_hb);
      int n4 = N * DF / 4;
      convert_bf16_kernel<<<(n4 + 255) / 256, 256, 0, stream>>>(
          (const float4*)H, Hb, n4);
      hist2_kernel<<<(E + 255) / 256, 256, 0, stream>>>(edst, cnt, gcnt, E);
      // bucket-group scan chain
      scan1_kernel<<<nbA, 256, 0, stream>>>(gcnt, gbase, bsumA, NBKG);
      scan2_kernel<<<1, 128, 0, stream>>>(bsumA, nbA);
      scan3g_kernel<<<(NBKG + 255) / 256, 256, 0, stream>>>(gbase, bsumA, gcur,
                                                            NBKG, nbA);
      // per-node scan chain
      scan1_kernel<<<nbB, 256, 0, stream>>>(cnt, rowptr, bsumB, N);
      scan2_kernel<<<1, 128, 0, stream>>>(bsumB, nbB);
      scan3n_kernel<<<(N + 255) / 256, 256, 0, stream>>>(rowptr, bsumB, N, nbB);
      // append + bucket-local reorder
      append_kernel<<<(E + 255) / 256, 256, 0, stream>>>(esrc, edst, ew, gcur,
                                                         payload, E);
      reorder_kernel<<<nbk, 256, 0, stream>>>(payload, gbase, rowptr, csr, N);
      pull_csr_kernel<1><<<(N + 3) / 4, 256, 0, stream>>>(
          (const void*)Hb, rowptr, csr, h, N);
    } else {
      hist2_kernel<<<(E + 255) / 256, 256, 0, stream>>>(edst, cnt, gcnt, E);
      scan1_kernel<<<nbA, 256, 0, stream>>>(gcnt, gbase, bsumA, NBKG);
      scan2_kernel<<<1, 128, 0, stream>>>(bsumA, nbA);
      scan3g_kernel<<<(NBKG + 255) / 256, 256, 0, stream>>>(gbase, bsumA, gcur,
                                                            NBKG, nbA);
      scan1_kernel<<<nbB, 256, 0, stream>>>(cnt, rowptr, bsumB, N);
      scan2_kernel<<<1, 128, 0, stream>>>(bsumB, nbB);
      scan3n_kernel<<<(N + 255) / 256, 256, 0, stream>>>(rowptr, bsumB, N, nbB);
      append_kernel<<<(E + 255) / 256, 256, 0, stream>>>(esrc, edst, ew, gcur,
                                                         payload, E);
      reorder_kernel<<<nbk, 256, 0, stream>>>(payload, gbase, rowptr, csr, N);
      pull_csr_kernel<0><<<(N + 3) / 4, 256, 0, stream>>>(
          (const void*)H, rowptr, csr, h, N);
    }
  } else {
    hipMemsetAsync(d_out, 0, (size_t)out_size * sizeof(float), stream);
    long long threads = (long long)E * 32;
    long long grid = (threads + 255) / 256;
    scatter_kernel<<<(int)grid, 256, 0, stream>>>(H, esrc, edst, ew, h, E);
  }

  fused_bn_gemm_gelu<<<(N + 15) / 16, 256, 0, stream>>>(h, gamma, beta, mean,
                                                        var, W, b, N);
}

// Round 8
// 343.567 us; speedup vs baseline: 8.1521x; 2.1376x over previous
//
#include <hip/hip_runtime.h>
#include <math.h>

// out = gelu( BN(segment_sum(H[src]*w, dst)) @ W + b ), exact gelu.
// N=100000, E=3200000, D=HIDDEN=128, all f32.
//
// Round-8: atomic-free CSR build (per-block LDS histograms).
//   K1: convert H -> bf16 (RNE)
//   K2: hist_blk    128 blocks; LDS hist over 1563 buckets; bcnt[k][b] (no atomics)
//   K3: scan1/2/3   over bcnt (bucket-major, 200K entries) -> gbase
//   K4: scatter_blk LDS cursors from gbase column; payload stores in ~128B runs
//   K5: reorder2    block/bucket: stage seg in LDS, 64-ctr hist+scan ->
//                   rowptr AND node-ordered csr (window-local traffic)
//   K6: pull_csr    wave/node, 8 independent bf16 row gathers in flight
//   K7: fused BN + (h @ W) + bias + exact GELU, in place on d_out
// ZERO per-edge global atomics anywhere.
// Fallback: push-based atomic scatter if ws too small.

#define DF 128
#define SCAN_ELEMS 1024
#define BKSH 6
#define BKNODES (1 << BKSH)
#define NB 128            // blocks for hist_blk / scatter_blk
#define CAP 4096          // reorder2 LDS staging entries (avg seg ~2048)

// ---------------- Tier C fallback ----------------
__global__ __launch_bounds__(256) void scatter_kernel(
    const float* __restrict__ H, const int* __restrict__ esrc,
    const int* __restrict__ edst, const float* __restrict__ ew,
    float* __restrict__ h, int E) {
  int tid = blockIdx.x * blockDim.x + threadIdx.x;
  int e = tid >> 5;
  int lane = tid & 31;
  if (e >= E) return;
  int s = esrc[e];
  int d = edst[e];
  float w = ew[e];
  const float4* Hs = reinterpret_cast<const float4*>(H + (size_t)s * DF);
  float4 v = Hs[lane];
  float* hd = h + (size_t)d * DF + lane * 4;
  atomicAdd(hd + 0, v.x * w);
  atomicAdd(hd + 1, v.y * w);
  atomicAdd(hd + 2, v.z * w);
  atomicAdd(hd + 3, v.w * w);
}

// ---------------- H -> bf16 (RNE) ----------------
__global__ __launch_bounds__(256) void convert_bf16_kernel(
    const float4* __restrict__ H4, ushort4* __restrict__ Hb, int n4) {
  int i = blockIdx.x * blockDim.x + threadIdx.x;
  if (i >= n4) return;
  float4 v = H4[i];
  auto cvt = [](float f) -> unsigned short {
    unsigned u = __float_as_uint(f);
    unsigned r = (u + 0x7FFFu + ((u >> 16) & 1u)) >> 16;
    return (unsigned short)r;
  };
  ushort4 o;
  o.x = cvt(v.x); o.y = cvt(v.y); o.z = cvt(v.z); o.w = cvt(v.w);
  Hb[i] = o;
}

// ---------------- per-block LDS bucket histogram (no global atomics) -------
__global__ __launch_bounds__(512) void hist_blk_kernel(
    const int* __restrict__ edst, int* __restrict__ bcnt,
    int E, int nbk, int chunk) {
  extern __shared__ int hcnt[];  // nbk counters
  int b = blockIdx.x;
  int t = threadIdx.x;
  for (int i = t; i < nbk; i += 512) hcnt[i] = 0;
  __syncthreads();
  int e0 = b * chunk;
  int e1 = min(E, e0 + chunk);
  for (int e = e0 + t; e < e1; e += 512)
    atomicAdd(&hcnt[edst[e] >> BKSH], 1);  // LDS atomic
  __syncthreads();
  for (int k = t; k < nbk; k += 512)
    bcnt[(size_t)k * NB + b] = hcnt[k];
}

// ---------------- scans ----------------
__global__ __launch_bounds__(256) void scan1_kernel(
    const int* __restrict__ cnt, int* __restrict__ pre,
    int* __restrict__ bsum, int N) {
  __shared__ int s[256];
  int t = threadIdx.x;
  int base = blockIdx.x * SCAN_ELEMS + t * 4;
  int v0 = (base + 0 < N) ? cnt[base + 0] : 0;
  int v1 = (base + 1 < N) ? cnt[base + 1] : 0;
  int v2 = (base + 2 < N) ? cnt[base + 2] : 0;
  int v3 = (base + 3 < N) ? cnt[base + 3] : 0;
  int tsum = v0 + v1 + v2 + v3;
  s[t] = tsum;
  __syncthreads();
  for (int off = 1; off < 256; off <<= 1) {
    int tmp = (t >= off) ? s[t - off] : 0;
    __syncthreads();
    s[t] += tmp;
    __syncthreads();
  }
  int run = s[t] - tsum;
  if (base + 0 < N) pre[base + 0] = run;
  run += v0;
  if (base + 1 < N) pre[base + 1] = run;
  run += v1;
  if (base + 2 < N) pre[base + 2] = run;
  run += v2;
  if (base + 3 < N) pre[base + 3] = run;
  if (t == 255) bsum[blockIdx.x] = s[255];
}

__global__ __launch_bounds__(256) void scan2_kernel(int* __restrict__ bsum, int nb) {
  __shared__ int s[256];
  int t = threadIdx.x;
  int v = (t < nb) ? bsum[t] : 0;
  s[t] = v;
  __syncthreads();
  for (int off = 1; off < 256; off <<= 1) {
    int tmp = (t >= off) ? s[t - off] : 0;
    __syncthreads();
    s[t] += tmp;
    __syncthreads();
  }
  if (t < nb) bsum[t] = s[t] - v;
  if (t == 255) bsum[nb] = s[255];
}

__global__ __launch_bounds__(256) void scan3_kernel(
    int* __restrict__ gbase, const int* __restrict__ bsum, int NBKG, int nb) {
  int i = blockIdx.x * blockDim.x + threadIdx.x;
  if (i < NBKG) gbase[i] += bsum[i >> 10];
  if (i == 0) gbase[NBKG] = bsum[nb];
}

// ---------------- scatter into bucket-sorted payload (LDS cursors) ---------
__global__ __launch_bounds__(512) void scatter_blk_kernel(
    const int* __restrict__ esrc, const int* __restrict__ edst,
    const float* __restrict__ ew, const int* __restrict__ gbase,
    uint2* __restrict__ payload, int E, int nbk, int chunk) {
  extern __shared__ int cur[];  // nbk cursors
  int b = blockIdx.x;
  int t = threadIdx.x;
  for (int k = t; k < nbk; k += 512) cur[k] = gbase[(size_t)k * NB + b];
  __syncthreads();
  int e0 = b * chunk;
  int e1 = min(E, e0 + chunk);
  for (int e = e0 + t; e < e1; e += 512) {
    int d = edst[e];
    int k = d >> BKSH;
    int pos = atomicAdd(&cur[k], 1);  // LDS atomic
    uint2 v;
    v.x = (unsigned)esrc[e] | ((unsigned)(d & (BKNODES - 1)) << 17);
    v.y = __float_as_uint(ew[e]);
    payload[pos] = v;
  }
}

// ---------------- reorder bucket segment -> node-ordered csr + rowptr ------
__global__ __launch_bounds__(256) void reorder2_kernel(
    const uint2* __restrict__ payload, const int* __restrict__ gbase,
    uint2* __restrict__ csr, int* __restrict__ rowptr,
    int N, int nbk, int E) {
  __shared__ uint2 stage[CAP];      // 32 KB
  __shared__ int cnt[BKNODES];
  __shared__ int s64[BKNODES];
  __shared__ int cur[BKNODES];
  int bk = blockIdx.x;
  int t = threadIdx.x;
  int base = gbase[(size_t)bk * NB];
  int end  = gbase[(size_t)(bk + 1) * NB];
  int len = end - base;
  bool fit = (len <= CAP);

  if (t < BKNODES) cnt[t] = 0;
  __syncthreads();
  if (fit) {
    for (int j = t; j < len; j += 256) {
      uint2 m = payload[base + j];
      stage[j] = m;
      atomicAdd(&cnt[m.x >> 17], 1);
    }
  } else {
    for (int j = t; j < len; j += 256)
      atomicAdd(&cnt[payload[base + j].x >> 17], 1);
  }
  __syncthreads();
  // inclusive scan of cnt[64]
  if (t < BKNODES) s64[t] = cnt[t];
  __syncthreads();
  for (int off = 1; off < BKNODES; off <<= 1) {
    int tmp = 0;
    if (t < BKNODES && t >= off) tmp = s64[t - off];
    __syncthreads();
    if (t < BKNODES) s64[t] += tmp;
    __syncthreads();
  }
  if (t < BKNODES) {
    int ex = s64[t] - cnt[t];  // exclusive prefix
    cur[t] = ex;
    int node = (bk << BKSH) + t;
    if (node < N) rowptr[node] = base + ex;
  }
  if (bk == nbk - 1 && t == 0) rowptr[N] = E;
  __syncthreads();
  if (fit) {
    for (int j = t; j < len; j += 256) {
      uint2 m = stage[j];
      int dl = (int)(m.x >> 17);
      int pos = atomicAdd(&cur[dl], 1);
      uint2 o;
      o.x = m.x & 0x1FFFFu;
      o.y = m.y;
      csr[(size_t)base + pos] = o;
    }
  } else {
    for (int j = t; j < len; j += 256) {
      uint2 m = payload[base + j];
      int dl = (int)(m.x >> 17);
      int pos = atomicAdd(&cur[dl], 1);
      uint2 o;
      o.x = m.x & 0x1FFFFu;
      o.y = m.y;
      csr[(size_t)base + pos] = o;
    }
  }
}

// ---------------- CSR pull (round-5 verified): wave per node ----------------
template <int BF16>
__global__ __launch_bounds__(256) void pull_csr_kernel(
    const void* __restrict__ Hv, const int* __restrict__ rowptr,
    const uint2* __restrict__ csr_sw, float* __restrict__ h, int N) {
  int wave = threadIdx.x >> 6;
  int lane = threadIdx.x & 63;
  int node = blockIdx.x * 4 + wave;
  if (node >= N) return;
  const unsigned* __restrict__ Hb = (const unsigned*)Hv;
  const float2* __restrict__ H2 = (const float2*)Hv;

  int rs = rowptr[node];
  int re = rowptr[node + 1];
  float ax = 0.0f, ay = 0.0f;

  int j = rs;
  for (; j + 8 <= re; j += 8) {
    uint2 m[8];
#pragma unroll
    for (int k = 0; k < 8; ++k) m[k] = csr_sw[j + k];
    float lo[8], hi[8];
#pragma unroll
    for (int k = 0; k < 8; ++k) {
      if (BF16) {
        unsigned p = Hb[(size_t)m[k].x * 64 + lane];
        lo[k] = __uint_as_float(p << 16);
        hi[k] = __uint_as_float(p & 0xFFFF0000u);
      } else {
        float2 u = H2[(size_t)m[k].x * 64 + lane];
        lo[k] = u.x;
        hi[k] = u.y;
      }
    }
#pragma unroll
    for (int k = 0; k < 8; ++k) {
      float w = __uint_as_float(m[k].y);
      ax = fmaf(lo[k], w, ax);
      ay = fmaf(hi[k], w, ay);
    }
  }
  for (; j < re; ++j) {
    uint2 m = csr_sw[j];
    float w = __uint_as_float(m.y);
    if (BF16) {
      unsigned p = Hb[(size_t)m.x * 64 + lane];
      ax = fmaf(__uint_as_float(p << 16), w, ax);
      ay = fmaf(__uint_as_float(p & 0xFFFF0000u), w, ay);
    } else {
      float2 u = H2[(size_t)m.x * 64 + lane];
      ax = fmaf(u.x, w, ax);
      ay = fmaf(u.y, w, ay);
    }
  }

  float2 r;
  r.x = ax;
  r.y = ay;
  reinterpret_cast<float2*>(h)[(size_t)node * 64 + lane] = r;
}

// ---------------- fused BN + GEMM + GELU (verified rounds 1-7) --------------
__global__ __launch_bounds__(256) void fused_bn_gemm_gelu(
    float* __restrict__ hout, const float* __restrict__ gamma,
    const float* __restrict__ beta, const float* __restrict__ mean,
    const float* __restrict__ var, const float* __restrict__ W,
    const float* __restrict__ b, int N) {
  __shared__ float s_s[DF];
  __shared__ float s_t[DF];
  __shared__ float s_hb[16][DF];
  __shared__ float s_W[32][DF];

  int t = threadIdx.x;
  if (t < DF) {
    float sv = gamma[t] * rsqrtf(var[t] + 1e-3f);
    s_s[t] = sv;
    s_t[t] = beta[t] - mean[t] * sv;
  }
  __syncthreads();

  int n0 = blockIdx.x * 16;
  for (int i = t; i < 16 * DF; i += 256) {
    int r = i >> 7;
    int c = i & (DF - 1);
    int node = n0 + r;
    float hv = (node < N) ? hout[(size_t)node * DF + c] : 0.0f;
    s_hb[r][c] = hv * s_s[c] + s_t[c];
  }

  float acc[8];
#pragma unroll
  for (int i = 0; i < 8; i++) acc[i] = 0.0f;

  int col = t & (DF - 1);
  int half = t >> 7;

  for (int kc = 0; kc < DF; kc += 32) {
    __syncthreads();
    for (int i = t; i < 32 * DF; i += 256) {
      int r = i >> 7;
      int c = i & (DF - 1);
      s_W[r][c] = W[(size_t)(kc + r) * DF + c];
    }
    __syncthreads();
#pragma unroll
    for (int kk = 0; kk < 32; kk++) {
      float wv = s_W[kk][col];
#pragma unroll
      for (int i = 0; i < 8; i++) {
        acc[i] += s_hb[half + i * 2][kc + kk] * wv;
      }
    }
  }

  float bb = b[col];
#pragma unroll
  for (int i = 0; i < 8; i++) {
    int node = n0 + half + i * 2;
    if (node < N) {
      float x = acc[i] + bb;
      float g = 0.5f * x * (1.0f + erff(x * 0.70710678118654752440f));
      hout[(size_t)node * DF + col] = g;
    }
  }
}

extern "C" void kernel_launch(void* const* d_in, const int* in_sizes, int n_in,
                              void* d_out, int out_size, void* d_ws, size_t ws_size,
                              hipStream_t stream) {
  const float* H     = (const float*)d_in[0];
  const int*   esrc  = (const int*)d_in[1];
  const int*   edst  = (const int*)d_in[2];
  const float* ew    = (const float*)d_in[3];
  const float* gamma = (const float*)d_in[4];
  const float* beta  = (const float*)d_in[5];
  const float* mean  = (const float*)d_in[6];
  const float* var   = (const float*)d_in[7];
  const float* W     = (const float*)d_in[8];
  const float* b     = (const float*)d_in[9];

  int N = in_sizes[0] / DF;
  int E = in_sizes[1];
  float* h = (float*)d_out;

  int nbk = (N + BKNODES - 1) / BKNODES;   // 1563 buckets
  int NBKG = nbk * NB;                      // 200064 scan elements
  int nbA = (NBKG + SCAN_ELEMS - 1) / SCAN_ELEMS;  // 196 <= 256
  int chunk = (E + NB - 1) / NB;            // 25000 edges per block

  size_t off = 0;
  auto alloc = [&](size_t bytes) {
    size_t o = off;
    off += (bytes + 255) & ~(size_t)255;
    return o;
  };
  size_t o_bcnt   = alloc((size_t)NBKG * 4);
  size_t o_gbase  = alloc((size_t)(NBKG + 1) * 4);
  size_t o_bsum   = alloc((size_t)(nbA + 1) * 4);
  size_t o_rowptr = alloc((size_t)(N + 1) * 4);
  size_t o_pl     = alloc((size_t)E * 8);
  size_t o_csr    = alloc((size_t)E * 8);
  size_t need_bin = off;
  size_t o_hb     = alloc((size_t)N * DF * 2);
  size_t need_bf16 = off;

  char* ws = (char*)d_ws;

  if (ws_size >= need_bin) {
    int* bcnt    = (int*)(ws + o_bcnt);
    int* gbase   = (int*)(ws + o_gbase);
    int* bsum    = (int*)(ws + o_bsum);
    int* rowptr  = (int*)(ws + o_rowptr);
    uint2* payload = (uint2*)(ws + o_pl);
    uint2* csr     = (uint2*)(ws + o_csr);
    bool tierA = (ws_size >= need_bf16);

    size_t lds_bytes = (size_t)nbk * 4;

    if (tierA) {
      ushort4* Hb = (ushort4*)(ws + o_hb);
      int n4 = N * DF / 4;
      convert_bf16_kernel<<<(n4 + 255) / 256, 256, 0, stream>>>(
          (const float4*)H, Hb, n4);
      hist_blk_kernel<<<NB, 512, lds_bytes, stream>>>(edst, bcnt, E, nbk, chunk);
      scan1_kernel<<<nbA, 256, 0, stream>>>(bcnt, gbase, bsum, NBKG);
      scan2_kernel<<<1, 256, 0, stream>>>(bsum, nbA);
      scan3_kernel<<<(NBKG + 256) / 256, 256, 0, stream>>>(gbase, bsum, NBKG, nbA);
      scatter_blk_kernel<<<NB, 512, lds_bytes, stream>>>(esrc, edst, ew, gbase,
                                                         payload, E, nbk, chunk);
      reorder2_kernel<<<nbk, 256, 0, stream>>>(payload, gbase, csr, rowptr,
                                               N, nbk, E);
      pull_csr_kernel<1><<<(N + 3) / 4, 256, 0, stream>>>(
          (const void*)Hb, rowptr, csr, h, N);
    } else {
      hist_blk_kernel<<<NB, 512, lds_bytes, stream>>>(edst, bcnt, E, nbk, chunk);
      scan1_kernel<<<nbA, 256, 0, stream>>>(bcnt, gbase, bsum, NBKG);
      scan2_kernel<<<1, 256, 0, stream>>>(bsum, nbA);
      scan3_kernel<<<(NBKG + 256) / 256, 256, 0, stream>>>(gbase, bsum, NBKG, nbA);
      scatter_blk_kernel<<<NB, 512, lds_bytes, stream>>>(esrc, edst, ew, gbase,
                                                         payload, E, nbk, chunk);
      reorder2_kernel<<<nbk, 256, 0, stream>>>(payload, gbase, csr, rowptr,
                                               N, nbk, E);
      pull_csr_kernel<0><<<(N + 3) / 4, 256, 0, stream>>>(
          (const void*)H, rowptr, csr, h, N);
    }
  } else {
    hipMemsetAsync(d_out, 0, (size_t)out_size * sizeof(float), stream);
    long long threads = (long long)E * 32;
    long long grid = (threads + 255) / 256;
    scatter_kernel<<<(int)grid, 256, 0, stream>>>(H, esrc, edst, ew, h, E);
  }

  fused_bn_gemm_gelu<<<(N + 15) / 16, 256, 0, stream>>>(h, gamma, beta, mean,
                                                        var, W, b, N);
}

// Round 9
// 258.113 us; speedup vs baseline: 10.8511x; 1.3311x over previous
//
#include <hip/hip_runtime.h>
#include <math.h>

// out = gelu( BN(segment_sum(H[src]*w, dst)) @ W + b ), exact gelu.
// N=100000, E=3200000, D=HIDDEN=128, all f32.
//
// Round-9: MFMA GEMM with BN folded into weights.
//   K1: convert H -> bf16 (RNE)
//   K2: prep_w2frag  W2[k][c]=s[k]*W[k][c] in MFMA B-fragment order (bf16)
//       prep_bias2   bias2[c]=b[c]+sum_k t[k]*W[k][c]
//   K3: hist_blk / scans / scatter_blk / reorder2  (atomic-free CSR, round 8)
//   K4: pull_csr_b   wave/node, 8-deep bf16 gathers, writes h as PACKED BF16
//                    (into the dead payload buffer -> zero extra ws)
//   K5: mfma_gemm_gelu  16x16x32 bf16 MFMA, W2 staged in LDS, fused GELU
// Fallbacks: tier B = f32 pull + VALU GEMM; tier C = atomic scatter.

#define DF 128
#define SCAN_ELEMS 1024
#define BKSH 6
#define BKNODES (1 << BKSH)
#define NB 128
#define CAP 4096

typedef short short8 __attribute__((ext_vector_type(8)));
typedef float f32x4 __attribute__((ext_vector_type(4)));

__device__ __forceinline__ unsigned short f32_to_bf16_rne(float f) {
  unsigned u = __float_as_uint(f);
  return (unsigned short)((u + 0x7FFFu + ((u >> 16) & 1u)) >> 16);
}

// ---------------- Tier C fallback ----------------
__global__ __launch_bounds__(256) void scatter_kernel(
    const float* __restrict__ H, const int* __restrict__ esrc,
    const int* __restrict__ edst, const float* __restrict__ ew,
    float* __restrict__ h, int E) {
  int tid = blockIdx.x * blockDim.x + threadIdx.x;
  int e = tid >> 5;
  int lane = tid & 31;
  if (e >= E) return;
  int s = esrc[e];
  int d = edst[e];
  float w = ew[e];
  const float4* Hs = reinterpret_cast<const float4*>(H + (size_t)s * DF);
  float4 v = Hs[lane];
  float* hd = h + (size_t)d * DF + lane * 4;
  atomicAdd(hd + 0, v.x * w);
  atomicAdd(hd + 1, v.y * w);
  atomicAdd(hd + 2, v.z * w);
  atomicAdd(hd + 3, v.w * w);
}

// ---------------- H -> bf16 (RNE) ----------------
__global__ __launch_bounds__(256) void convert_bf16_kernel(
    const float4* __restrict__ H4, ushort4* __restrict__ Hb, int n4) {
  int i = blockIdx.x * blockDim.x + threadIdx.x;
  if (i >= n4) return;
  float4 v = H4[i];
  ushort4 o;
  o.x = f32_to_bf16_rne(v.x);
  o.y = f32_to_bf16_rne(v.y);
  o.z = f32_to_bf16_rne(v.z);
  o.w = f32_to_bf16_rne(v.w);
  Hb[i] = o;
}

// ---------------- BN-folded weight prep ----------------
// W2frag[((ct*4+kt)*64+l)*8+i] = bf16( s[k] * W[k][c] ),
//   k = kt*32 + (l>>4)*8 + i, c = ct*16 + (l&15)
__global__ __launch_bounds__(256) void prep_w2frag_kernel(
    const float* __restrict__ W, const float* __restrict__ gamma,
    const float* __restrict__ var, unsigned short* __restrict__ W2frag) {
  int idx = blockIdx.x * blockDim.x + threadIdx.x;  // 0..16383
  int i = idx & 7;
  int l = (idx >> 3) & 63;
  int kt = (idx >> 9) & 3;
  int ct = idx >> 11;
  int k = kt * 32 + (l >> 4) * 8 + i;
  int c = ct * 16 + (l & 15);
  float s = gamma[k] * rsqrtf(var[k] + 1e-3f);
  W2frag[idx] = f32_to_bf16_rne(s * W[(size_t)k * DF + c]);
}

// bias2[c] = b[c] + sum_k t[k]*W[k][c],  t[k] = beta[k] - mean[k]*s[k]
__global__ __launch_bounds__(128) void prep_bias2_kernel(
    const float* __restrict__ W, const float* __restrict__ gamma,
    const float* __restrict__ beta, const float* __restrict__ mean,
    const float* __restrict__ var, const float* __restrict__ b,
    float* __restrict__ bias2) {
  int c = threadIdx.x;
  float acc = b[c];
  for (int k = 0; k < DF; ++k) {
    float s = gamma[k] * rsqrtf(var[k] + 1e-3f);
    float t = beta[k] - mean[k] * s;
    acc += t * W[(size_t)k * DF + c];
  }
  bias2[c] = acc;
}

// ---------------- per-block LDS bucket histogram ----------------
__global__ __launch_bounds__(512) void hist_blk_kernel(
    const int* __restrict__ edst, int* __restrict__ bcnt,
    int E, int nbk, int chunk) {
  extern __shared__ int hcnt[];
  int b = blockIdx.x;
  int t = threadIdx.x;
  for (int i = t; i < nbk; i += 512) hcnt[i] = 0;
  __syncthreads();
  int e0 = b * chunk;
  int e1 = min(E, e0 + chunk);
  for (int e = e0 + t; e < e1; e += 512)
    atomicAdd(&hcnt[edst[e] >> BKSH], 1);
  __syncthreads();
  for (int k = t; k < nbk; k += 512)
    bcnt[(size_t)k * NB + b] = hcnt[k];
}

// ---------------- scans ----------------
__global__ __launch_bounds__(256) void scan1_kernel(
    const int* __restrict__ cnt, int* __restrict__ pre,
    int* __restrict__ bsum, int N) {
  __shared__ int s[256];
  int t = threadIdx.x;
  int base = blockIdx.x * SCAN_ELEMS + t * 4;
  int v0 = (base + 0 < N) ? cnt[base + 0] : 0;
  int v1 = (base + 1 < N) ? cnt[base + 1] : 0;
  int v2 = (base + 2 < N) ? cnt[base + 2] : 0;
  int v3 = (base + 3 < N) ? cnt[base + 3] : 0;
  int tsum = v0 + v1 + v2 + v3;
  s[t] = tsum;
  __syncthreads();
  for (int off = 1; off < 256; off <<= 1) {
    int tmp = (t >= off) ? s[t - off] : 0;
    __syncthreads();
    s[t] += tmp;
    __syncthreads();
  }
  int run = s[t] - tsum;
  if (base + 0 < N) pre[base + 0] = run;
  run += v0;
  if (base + 1 < N) pre[base + 1] = run;
  run += v1;
  if (base + 2 < N) pre[base + 2] = run;
  run += v2;
  if (base + 3 < N) pre[base + 3] = run;
  if (t == 255) bsum[blockIdx.x] = s[255];
}

__global__ __launch_bounds__(256) void scan2_kernel(int* __restrict__ bsum, int nb) {
  __shared__ int s[256];
  int t = threadIdx.x;
  int v = (t < nb) ? bsum[t] : 0;
  s[t] = v;
  __syncthreads();
  for (int off = 1; off < 256; off <<= 1) {
    int tmp = (t >= off) ? s[t - off] : 0;
    __syncthreads();
    s[t] += tmp;
    __syncthreads();
  }
  if (t < nb) bsum[t] = s[t] - v;
  if (t == 255) bsum[nb] = s[255];
}

__global__ __launch_bounds__(256) void scan3_kernel(
    int* __restrict__ gbase, const int* __restrict__ bsum, int NBKG, int nb) {
  int i = blockIdx.x * blockDim.x + threadIdx.x;
  if (i < NBKG) gbase[i] += bsum[i >> 10];
  if (i == 0) gbase[NBKG] = bsum[nb];
}

// ---------------- scatter into bucket-sorted payload ----------------
__global__ __launch_bounds__(512) void scatter_blk_kernel(
    const int* __restrict__ esrc, const int* __restrict__ edst,
    const float* __restrict__ ew, const int* __restrict__ gbase,
    uint2* __restrict__ payload, int E, int nbk, int chunk) {
  extern __shared__ int cur[];
  int b = blockIdx.x;
  int t = threadIdx.x;
  for (int k = t; k < nbk; k += 512) cur[k] = gbase[(size_t)k * NB + b];
  __syncthreads();
  int e0 = b * chunk;
  int e1 = min(E, e0 + chunk);
  for (int e = e0 + t; e < e1; e += 512) {
    int d = edst[e];
    int k = d >> BKSH;
    int pos = atomicAdd(&cur[k], 1);
    uint2 v;
    v.x = (unsigned)esrc[e] | ((unsigned)(d & (BKNODES - 1)) << 17);
    v.y = __float_as_uint(ew[e]);
    payload[pos] = v;
  }
}

// ---------------- reorder bucket segment -> node-ordered csr + rowptr ------
__global__ __launch_bounds__(256) void reorder2_kernel(
    const uint2* __restrict__ payload, const int* __restrict__ gbase,
    uint2* __restrict__ csr, int* __restrict__ rowptr,
    int N, int nbk, int E) {
  __shared__ uint2 stage[CAP];
  __shared__ int cnt[BKNODES];
  __shared__ int s64[BKNODES];
  __shared__ int cur[BKNODES];
  int bk = blockIdx.x;
  int t = threadIdx.x;
  int base = gbase[(size_t)bk * NB];
  int end  = gbase[(size_t)(bk + 1) * NB];
  int len = end - base;
  bool fit = (len <= CAP);

  if (t < BKNODES) cnt[t] = 0;
  __syncthreads();
  if (fit) {
    for (int j = t; j < len; j += 256) {
      uint2 m = payload[base + j];
      stage[j] = m;
      atomicAdd(&cnt[m.x >> 17], 1);
    }
  } else {
    for (int j = t; j < len; j += 256)
      atomicAdd(&cnt[payload[base + j].x >> 17], 1);
  }
  __syncthreads();
  if (t < BKNODES) s64[t] = cnt[t];
  __syncthreads();
  for (int off = 1; off < BKNODES; off <<= 1) {
    int tmp = 0;
    if (t < BKNODES && t >= off) tmp = s64[t - off];
    __syncthreads();
    if (t < BKNODES) s64[t] += tmp;
    __syncthreads();
  }
  if (t < BKNODES) {
    int ex = s64[t] - cnt[t];
    cur[t] = ex;
    int node = (bk << BKSH) + t;
    if (node < N) rowptr[node] = base + ex;
  }
  if (bk == nbk - 1 && t == 0) rowptr[N] = E;
  __syncthreads();
  if (fit) {
    for (int j = t; j < len; j += 256) {
      uint2 m = stage[j];
      int dl = (int)(m.x >> 17);
      int pos = atomicAdd(&cur[dl], 1);
      uint2 o;
      o.x = m.x & 0x1FFFFu;
      o.y = m.y;
      csr[(size_t)base + pos] = o;
    }
  } else {
    for (int j = t; j < len; j += 256) {
      uint2 m = payload[base + j];
      int dl = (int)(m.x >> 17);
      int pos = atomicAdd(&cur[dl], 1);
      uint2 o;
      o.x = m.x & 0x1FFFFu;
      o.y = m.y;
      csr[(size_t)base + pos] = o;
    }
  }
}

// ---------------- CSR pull, bf16 gather, PACKED BF16 output ----------------
__global__ __launch_bounds__(256) void pull_csr_b_kernel(
    const unsigned* __restrict__ Hb, const int* __restrict__ rowptr,
    const uint2* __restrict__ csr_sw, unsigned* __restrict__ hb_out, int N) {
  int wave = threadIdx.x >> 6;
  int lane = threadIdx.x & 63;
  int node = blockIdx.x * 4 + wave;
  if (node >= N) return;

  int rs = rowptr[node];
  int re = rowptr[node + 1];
  float ax = 0.0f, ay = 0.0f;

  int j = rs;
  for (; j + 8 <= re; j += 8) {
    uint2 m[8];
#pragma unroll
    for (int k = 0; k < 8; ++k) m[k] = csr_sw[j + k];
    float lo[8], hi[8];
#pragma unroll
    for (int k = 0; k < 8; ++k) {
      unsigned p = Hb[(size_t)m[k].x * 64 + lane];
      lo[k] = __uint_as_float(p << 16);
      hi[k] = __uint_as_float(p & 0xFFFF0000u);
    }
#pragma unroll
    for (int k = 0; k < 8; ++k) {
      float w = __uint_as_float(m[k].y);
      ax = fmaf(lo[k], w, ax);
      ay = fmaf(hi[k], w, ay);
    }
  }
  for (; j < re; ++j) {
    uint2 m = csr_sw[j];
    float w = __uint_as_float(m.y);
    unsigned p = Hb[(size_t)m.x * 64 + lane];
    ax = fmaf(__uint_as_float(p << 16), w, ax);
    ay = fmaf(__uint_as_float(p & 0xFFFF0000u), w, ay);
  }

  unsigned pack = (unsigned)f32_to_bf16_rne(ax) |
                  ((unsigned)f32_to_bf16_rne(ay) << 16);
  hb_out[(size_t)node * 64 + lane] = pack;
}

// ---------------- f32 CSR pull (tier B fallback) ----------------
__global__ __launch_bounds__(256) void pull_csr_f32_kernel(
    const float2* __restrict__ H2, const int* __restrict__ rowptr,
    const uint2* __restrict__ csr_sw, float* __restrict__ h, int N) {
  int wave = threadIdx.x >> 6;
  int lane = threadIdx.x & 63;
  int node = blockIdx.x * 4 + wave;
  if (node >= N) return;
  int rs = rowptr[node];
  int re = rowptr[node + 1];
  float ax = 0.0f, ay = 0.0f;
  for (int j = rs; j < re; ++j) {
    uint2 m = csr_sw[j];
    float w = __uint_as_float(m.y);
    float2 u = H2[(size_t)m.x * 64 + lane];
    ax = fmaf(u.x, w, ax);
    ay = fmaf(u.y, w, ay);
  }
  float2 r;
  r.x = ax;
  r.y = ay;
  reinterpret_cast<float2*>(h)[(size_t)node * 64 + lane] = r;
}

// ---------------- MFMA GEMM + GELU (BN pre-folded) ----------------
// block = 256 thr = 4 waves; 64 rows/block; wave w -> rows [w*16, w*16+16)
__global__ __launch_bounds__(256) void mfma_gemm_gelu_kernel(
    const unsigned short* __restrict__ hb,      // [N][128] bf16
    const unsigned short* __restrict__ W2frag,  // fragment-ordered bf16
    const float* __restrict__ bias2,            // [128]
    float* __restrict__ out, int N) {
  __shared__ unsigned short sW[8 * 4 * 64 * 8];  // 32 KB

  int t = threadIdx.x;
  {
    const uint4* src = (const uint4*)W2frag;
    uint4* dst = (uint4*)sW;
    for (int i = t; i < 2048; i += 256) dst[i] = src[i];
  }
  __syncthreads();

  int wid = t >> 6;
  int l = t & 63;
  int row0 = blockIdx.x * 64 + wid * 16;

  // A fragments: row = row0 + (l&15), k = kt*32 + (l>>4)*8 + i
  int arow = row0 + (l & 15);
  if (arow >= N) arow = N - 1;  // clamp (stores guarded)
  const short8* hrow = (const short8*)(hb + (size_t)arow * DF);
  int asub = l >> 4;
  short8 a[4];
#pragma unroll
  for (int kt = 0; kt < 4; ++kt) a[kt] = hrow[kt * 4 + asub];

  const short8* wf = (const short8*)sW;
  int orow = (l >> 4) * 4;  // C/D: row=(lane>>4)*4+reg, col=lane&15 (m89)
  int ocol = l & 15;

#pragma unroll
  for (int ct = 0; ct < 8; ++ct) {
    f32x4 acc = {0.0f, 0.0f, 0.0f, 0.0f};
#pragma unroll
    for (int kt = 0; kt < 4; ++kt) {
      short8 bfr = wf[(ct * 4 + kt) * 64 + l];
      acc = __builtin_amdgcn_mfma_f32_16x16x32_bf16(a[kt], bfr, acc, 0, 0, 0);
    }
    int col = ct * 16 + ocol;
    float bb = bias2[col];
#pragma unroll
    for (int r = 0; r < 4; ++r) {
      int row = row0 + orow + r;
      if (row < N) {
        float x = acc[r] + bb;
        float g = 0.5f * x * (1.0f + erff(x * 0.70710678118654752440f));
        out[(size_t)row * DF + col] = g;
      }
    }
  }
}

// ---------------- VALU BN+GEMM+GELU (tier B/C fallback) ----------------
__global__ __launch_bounds__(256) void fused_bn_gemm_gelu(
    float* __restrict__ hout, const float* __restrict__ gamma,
    const float* __restrict__ beta, const float* __restrict__ mean,
    const float* __restrict__ var, const float* __restrict__ W,
    const float* __restrict__ b, int N) {
  __shared__ float s_s[DF];
  __shared__ float s_t[DF];
  __shared__ float s_hb[16][DF];
  __shared__ float s_W[32][DF];

  int t = threadIdx.x;
  if (t < DF) {
    float sv = gamma[t] * rsqrtf(var[t] + 1e-3f);
    s_s[t] = sv;
    s_t[t] = beta[t] - mean[t] * sv;
  }
  __syncthreads();

  int n0 = blockIdx.x * 16;
  for (int i = t; i < 16 * DF; i += 256) {
    int r = i >> 7;
    int c = i & (DF - 1);
    int node = n0 + r;
    float hv = (node < N) ? hout[(size_t)node * DF + c] : 0.0f;
    s_hb[r][c] = hv * s_s[c] + s_t[c];
  }

  float acc[8];
#pragma unroll
  for (int i = 0; i < 8; i++) acc[i] = 0.0f;

  int col = t & (DF - 1);
  int half = t >> 7;

  for (int kc = 0; kc < DF; kc += 32) {
    __syncthreads();
    for (int i = t; i < 32 * DF; i += 256) {
      int r = i >> 7;
      int c = i & (DF - 1);
      s_W[r][c] = W[(size_t)(kc + r) * DF + c];
    }
    __syncthreads();
#pragma unroll
    for (int kk = 0; kk < 32; kk++) {
      float wv = s_W[kk][col];
#pragma unroll
      for (int i = 0; i < 8; i++) {
        acc[i] += s_hb[half + i * 2][kc + kk] * wv;
      }
    }
  }

  float bb = b[col];
#pragma unroll
  for (int i = 0; i < 8; i++) {
    int node = n0 + half + i * 2;
    if (node < N) {
      float x = acc[i] + bb;
      float g = 0.5f * x * (1.0f + erff(x * 0.70710678118654752440f));
      hout[(size_t)node * DF + col] = g;
    }
  }
}

extern "C" void kernel_launch(void* const* d_in, const int* in_sizes, int n_in,
                              void* d_out, int out_size, void* d_ws, size_t ws_size,
                              hipStream_t stream) {
  const float* H     = (const float*)d_in[0];
  const int*   esrc  = (const int*)d_in[1];
  const int*   edst  = (const int*)d_in[2];
  const float* ew    = (const float*)d_in[3];
  const float* gamma = (const float*)d_in[4];
  const float* beta  = (const float*)d_in[5];
  const float* mean  = (const float*)d_in[6];
  const float* var   = (const float*)d_in[7];
  const float* W     = (const float*)d_in[8];
  const float* b     = (const float*)d_in[9];

  int N = in_sizes[0] / DF;
  int E = in_sizes[1];
  float* h = (float*)d_out;

  int nbk = (N + BKNODES - 1) / BKNODES;
  int NBKG = nbk * NB;
  int nbA = (NBKG + SCAN_ELEMS - 1) / SCAN_ELEMS;
  int chunk = (E + NB - 1) / NB;

  size_t off = 0;
  auto alloc = [&](size_t bytes) {
    size_t o = off;
    off += (bytes + 255) & ~(size_t)255;
    return o;
  };
  size_t o_bcnt   = alloc((size_t)NBKG * 4);
  size_t o_gbase  = alloc((size_t)(NBKG + 1) * 4);
  size_t o_bsum   = alloc((size_t)(nbA + 1) * 4);
  size_t o_rowptr = alloc((size_t)(N + 1) * 4);
  size_t o_w2     = alloc((size_t)16384 * 2);
  size_t o_bias2  = alloc((size_t)DF * 4);
  size_t o_pl     = alloc((size_t)E * 8);        // reused as bf16 h after reorder2
  size_t o_csr    = alloc((size_t)E * 8);
  size_t need_bin = off;
  size_t o_hb     = alloc((size_t)N * DF * 2);
  size_t need_bf16 = off;

  char* ws = (char*)d_ws;

  if (ws_size >= need_bin) {
    int* bcnt    = (int*)(ws + o_bcnt);
    int* gbase   = (int*)(ws + o_gbase);
    int* bsum    = (int*)(ws + o_bsum);
    int* rowptr  = (int*)(ws + o_rowptr);
    unsigned short* W2frag = (unsigned short*)(ws + o_w2);
    float* bias2 = (float*)(ws + o_bias2);
    uint2* payload = (uint2*)(ws + o_pl);
    uint2* csr     = (uint2*)(ws + o_csr);
    bool tierA = (ws_size >= need_bf16 && (size_t)N * DF * 2 <= (size_t)E * 8);

    size_t lds_bytes = (size_t)nbk * 4;

    if (tierA) {
      ushort4* Hb = (ushort4*)(ws + o_hb);
      int n4 = N * DF / 4;
      convert_bf16_kernel<<<(n4 + 255) / 256, 256, 0, stream>>>(
          (const float4*)H, Hb, n4);
      prep_w2frag_kernel<<<64, 256, 0, stream>>>(W, gamma, var, W2frag);
      prep_bias2_kernel<<<1, 128, 0, stream>>>(W, gamma, beta, mean, var, b,
                                               bias2);
      hist_blk_kernel<<<NB, 512, lds_bytes, stream>>>(edst, bcnt, E, nbk, chunk);
      scan1_kernel<<<nbA, 256, 0, stream>>>(bcnt, gbase, bsum, NBKG);
      scan2_kernel<<<1, 256, 0, stream>>>(bsum, nbA);
      scan3_kernel<<<(NBKG + 256) / 256, 256, 0, stream>>>(gbase, bsum, NBKG, nbA);
      scatter_blk_kernel<<<NB, 512, lds_bytes, stream>>>(esrc, edst, ew, gbase,
                                                         payload, E, nbk, chunk);
      reorder2_kernel<<<nbk, 256, 0, stream>>>(payload, gbase, csr, rowptr,
                                               N, nbk, E);
      // payload is now dead -> reuse its space for bf16 h
      unsigned* hb_out = (unsigned*)(ws + o_pl);
      pull_csr_b_kernel<<<(N + 3) / 4, 256, 0, stream>>>(
          (const unsigned*)Hb, rowptr, csr, hb_out, N);
      mfma_gemm_gelu_kernel<<<(N + 63) / 64, 256, 0, stream>>>(
          (const unsigned short*)hb_out, W2frag, bias2, (float*)d_out, N);
    } else {
      hist_blk_kernel<<<NB, 512, lds_bytes, stream>>>(edst, bcnt, E, nbk, chunk);
      scan1_kernel<<<nbA, 256, 0, stream>>>(bcnt, gbase, bsum, NBKG);
      scan2_kernel<<<1, 256, 0, stream>>>(bsum, nbA);
      scan3_kernel<<<(NBKG + 256) / 256, 256, 0, stream>>>(gbase, bsum, NBKG, nbA);
      scatter_blk_kernel<<<NB, 512, lds_bytes, stream>>>(esrc, edst, ew, gbase,
                                                         payload, E, nbk, chunk);
      reorder2_kernel<<<nbk, 256, 0, stream>>>(payload, gbase, csr, rowptr,
                                               N, nbk, E);
      pull_csr_f32_kernel<<<(N + 3) / 4, 256, 0, stream>>>(
          (const float2*)H, rowptr, csr, h, N);
      fused_bn_gemm_gelu<<<(N + 15) / 16, 256, 0, stream>>>(h, gamma, beta,
                                                            mean, var, W, b, N);
    }
  } else {
    hipMemsetAsync(d_out, 0, (size_t)out_size * sizeof(float), stream);
    long long threads = (long long)E * 32;
    long long grid = (threads + 255) / 256;
    scatter_kernel<<<(int)grid, 256, 0, stream>>>(H, esrc, edst, ew, h, E);
    fused_bn_gemm_gelu<<<(N + 15) / 16, 256, 0, stream>>>(h, gamma, beta,
                                                          mean, var, W, b, N);
  }
}

// Round 10
// 232.049 us; speedup vs baseline: 12.0699x; 1.1123x over previous
//
#include <hip/hip_runtime.h>
#include <math.h>

// out = gelu( BN(segment_sum(H[src]*w, dst)) @ W + b ), exact gelu.
// N=100000, E=3200000, D=HIDDEN=128, all f32.
//
// Round-10: fuse reorder+pull (csr never hits global); merge prep kernels;
//           fold scan2 into scan3. 7 kernels total.
//   K1: prep_all     H->bf16 (RNE), W2frag = diag(s)W in B-frag order, bias2
//   K2: hist_blk     128 blocks, LDS bucket hist -> bcnt[k][b] (no atomics)
//   K3: scan1        per-1024 exclusive scan -> gbase partial, bsum
//   K4: scan23       re-scan bsum in LDS per block, finalize gbase
//   K5: scatter_blk  LDS cursors, bucket-sorted payload (no global atomics)
//   K6: reorder_pull block/bucket (1024 thr): stage seg in LDS, node-sort in
//                    LDS, 16 waves x 4 nodes pull (8-deep gathers, LDS
//                    broadcast metadata), write PACKED BF16 h
//   K7: mfma_gemm_gelu  16x16x32 bf16 MFMA, BN folded, fused exact GELU
// Fallbacks: tier B = f32 CSR path + VALU GEMM; tier C = atomic scatter.

#define DF 128
#define SCAN_ELEMS 1024
#define BKSH 6
#define BKNODES (1 << BKSH)
#define NB 128
#define CAP 4096       // tier-B reorder2 staging
#define CAP2 3072      // reorder_pull LDS staging entries (mean 2048, 22 sigma)

typedef short short8 __attribute__((ext_vector_type(8)));
typedef float f32x4 __attribute__((ext_vector_type(4)));

__device__ __forceinline__ unsigned short f32_to_bf16_rne(float f) {
  unsigned u = __float_as_uint(f);
  return (unsigned short)((u + 0x7FFFu + ((u >> 16) & 1u)) >> 16);
}

// ---------------- Tier C fallback ----------------
__global__ __launch_bounds__(256) void scatter_kernel(
    const float* __restrict__ H, const int* __restrict__ esrc,
    const int* __restrict__ edst, const float* __restrict__ ew,
    float* __restrict__ h, int E) {
  int tid = blockIdx.x * blockDim.x + threadIdx.x;
  int e = tid >> 5;
  int lane = tid & 31;
  if (e >= E) return;
  int s = esrc[e];
  int d = edst[e];
  float w = ew[e];
  const float4* Hs = reinterpret_cast<const float4*>(H + (size_t)s * DF);
  float4 v = Hs[lane];
  float* hd = h + (size_t)d * DF + lane * 4;
  atomicAdd(hd + 0, v.x * w);
  atomicAdd(hd + 1, v.y * w);
  atomicAdd(hd + 2, v.z * w);
  atomicAdd(hd + 3, v.w * w);
}

// ---------------- fused prep: H->bf16, W2 fragments, bias2 ----------------
// W2frag[((ct*4+kt)*64+l)*8+i] = bf16( s[k]*W[k][c] ),
//   k = kt*32 + (l>>4)*8 + i, c = ct*16 + (l&15)
// bias2[c] = b[c] + sum_k (beta[k]-mean[k]*s[k]) * W[k][c]
__global__ __launch_bounds__(256) void prep_all_kernel(
    const float4* __restrict__ H4, ushort4* __restrict__ Hb, int n4,
    const float* __restrict__ W, const float* __restrict__ gamma,
    const float* __restrict__ beta, const float* __restrict__ mean,
    const float* __restrict__ var, const float* __restrict__ b,
    unsigned short* __restrict__ W2frag, float* __restrict__ bias2) {
  int idx = blockIdx.x * blockDim.x + threadIdx.x;
  if (idx < n4) {
    float4 v = H4[idx];
    ushort4 o;
    o.x = f32_to_bf16_rne(v.x);
    o.y = f32_to_bf16_rne(v.y);
    o.z = f32_to_bf16_rne(v.z);
    o.w = f32_to_bf16_rne(v.w);
    Hb[idx] = o;
  }
  if (idx < 16384) {
    int i = idx & 7;
    int l = (idx >> 3) & 63;
    int kt = (idx >> 9) & 3;
    int ct = idx >> 11;
    int k = kt * 32 + (l >> 4) * 8 + i;
    int c = ct * 16 + (l & 15);
    float s = gamma[k] * rsqrtf(var[k] + 1e-3f);
    W2frag[idx] = f32_to_bf16_rne(s * W[(size_t)k * DF + c]);
  } else if (idx < 16384 + DF) {
    int c = idx - 16384;
    float acc = b[c];
    for (int k = 0; k < DF; ++k) {
      float s = gamma[k] * rsqrtf(var[k] + 1e-3f);
      float t = beta[k] - mean[k] * s;
      acc += t * W[(size_t)k * DF + c];
    }
    bias2[c] = acc;
  }
}

// ---------------- per-block LDS bucket histogram ----------------
__global__ __launch_bounds__(512) void hist_blk_kernel(
    const int* __restrict__ edst, int* __restrict__ bcnt,
    int E, int nbk, int chunk) {
  extern __shared__ int hcnt[];
  int bblk = blockIdx.x;
  int t = threadIdx.x;
  for (int i = t; i < nbk; i += 512) hcnt[i] = 0;
  __syncthreads();
  int e0 = bblk * chunk;
  int e1 = min(E, e0 + chunk);
  for (int e = e0 + t; e < e1; e += 512)
    atomicAdd(&hcnt[edst[e] >> BKSH], 1);
  __syncthreads();
  for (int k = t; k < nbk; k += 512)
    bcnt[(size_t)k * NB + bblk] = hcnt[k];
}

// ---------------- scans ----------------
__global__ __launch_bounds__(256) void scan1_kernel(
    const int* __restrict__ cnt, int* __restrict__ pre,
    int* __restrict__ bsum, int N) {
  __shared__ int s[256];
  int t = threadIdx.x;
  int base = blockIdx.x * SCAN_ELEMS + t * 4;
  int v0 = (base + 0 < N) ? cnt[base + 0] : 0;
  int v1 = (base + 1 < N) ? cnt[base + 1] : 0;
  int v2 = (base + 2 < N) ? cnt[base + 2] : 0;
  int v3 = (base + 3 < N) ? cnt[base + 3] : 0;
  int tsum = v0 + v1 + v2 + v3;
  s[t] = tsum;
  __syncthreads();
  for (int off = 1; off < 256; off <<= 1) {
    int tmp = (t >= off) ? s[t - off] : 0;
    __syncthreads();
    s[t] += tmp;
    __syncthreads();
  }
  int run = s[t] - tsum;
  if (base + 0 < N) pre[base + 0] = run;
  run += v0;
  if (base + 1 < N) pre[base + 1] = run;
  run += v1;
  if (base + 2 < N) pre[base + 2] = run;
  run += v2;
  if (base + 3 < N) pre[base + 3] = run;
  if (t == 255) bsum[blockIdx.x] = s[255];
}

// scan2 folded in: every block re-scans bsum (nbA <= 256) in LDS.
__global__ __launch_bounds__(256) void scan23_kernel(
    int* __restrict__ gbase, const int* __restrict__ bsum, int NBKG, int nbA) {
  __shared__ int s[256];
  int t = threadIdx.x;
  int v = (t < nbA) ? bsum[t] : 0;
  s[t] = v;
  __syncthreads();
  for (int off = 1; off < 256; off <<= 1) {
    int tmp = (t >= off) ? s[t - off] : 0;
    __syncthreads();
    s[t] += tmp;
    __syncthreads();
  }
  int i = blockIdx.x * 256 + t;
  if (i < NBKG) {
    int blk = i >> 10;
    int add = (blk == 0) ? 0 : s[blk - 1];
    gbase[i] += add;
  }
  if (blockIdx.x == 0 && t == 0) gbase[NBKG] = s[nbA - 1];
}

// ---------------- scatter into bucket-sorted payload ----------------
__global__ __launch_bounds__(512) void scatter_blk_kernel(
    const int* __restrict__ esrc, const int* __restrict__ edst,
    const float* __restrict__ ew, const int* __restrict__ gbase,
    uint2* __restrict__ payload, int E, int nbk, int chunk) {
  extern __shared__ int cur[];
  int bblk = blockIdx.x;
  int t = threadIdx.x;
  for (int k = t; k < nbk; k += 512) cur[k] = gbase[(size_t)k * NB + bblk];
  __syncthreads();
  int e0 = bblk * chunk;
  int e1 = min(E, e0 + chunk);
  for (int e = e0 + t; e < e1; e += 512) {
    int d = edst[e];
    int k = d >> BKSH;
    int pos = atomicAdd(&cur[k], 1);
    uint2 v;
    v.x = (unsigned)esrc[e] | ((unsigned)(d & (BKNODES - 1)) << 17);
    v.y = __float_as_uint(ew[e]);
    payload[pos] = v;
  }
}

// ---------------- fused reorder + pull: csr stays in LDS ----------------
// 1024 thr = 16 waves; block per bucket; wave w handles nodes dl=w*4..w*4+3.
__global__ __launch_bounds__(1024, 8) void reorder_pull_kernel(
    const unsigned* __restrict__ Hb, const uint2* __restrict__ payload,
    const int* __restrict__ gbase, unsigned* __restrict__ hb_out, int N) {
  __shared__ uint2 stage[CAP2];    // 24 KB
  __shared__ uint2 sorted[CAP2];   // 24 KB
  __shared__ int cnt[BKNODES];
  __shared__ int scn[BKNODES];
  __shared__ int cur[BKNODES];
  int bk = blockIdx.x;
  int t = threadIdx.x;
  int base = gbase[(size_t)bk * NB];
  int end  = gbase[(size_t)(bk + 1) * NB];
  int len = end - base;
  int wid = t >> 6;
  int lane = t & 63;

  if (len <= CAP2) {
    if (t < BKNODES) cnt[t] = 0;
    __syncthreads();
    for (int j = t; j < len; j += 1024) {
      uint2 m = payload[base + j];
      stage[j] = m;
      atomicAdd(&cnt[m.x >> 17], 1);
    }
    __syncthreads();
    if (t < BKNODES) scn[t] = cnt[t];
    __syncthreads();
    for (int off = 1; off < BKNODES; off <<= 1) {
      int tmp = 0;
      if (t < BKNODES && t >= off) tmp = scn[t - off];
      __syncthreads();
      if (t < BKNODES) scn[t] += tmp;
      __syncthreads();
    }
    if (t < BKNODES) cur[t] = scn[t] - cnt[t];
    __syncthreads();
    for (int j = t; j < len; j += 1024) {
      uint2 m = stage[j];
      int dl = (int)(m.x >> 17);
      int pos = atomicAdd(&cur[dl], 1);
      uint2 o;
      o.x = m.x & 0x1FFFFu;
      o.y = m.y;
      sorted[pos] = o;
    }
    __syncthreads();

#pragma unroll
    for (int i = 0; i < 4; ++i) {
      int dl = wid * 4 + i;
      int node = (bk << BKSH) + dl;
      if (node >= N) break;
      int s1 = scn[dl];
      int s0 = s1 - cnt[dl];
      float ax = 0.0f, ay = 0.0f;
      int j = s0;
      for (; j + 8 <= s1; j += 8) {
        uint2 m[8];
#pragma unroll
        for (int k = 0; k < 8; ++k) m[k] = sorted[j + k];  // LDS broadcast
        float lo[8], hi[8];
#pragma unroll
        for (int k = 0; k < 8; ++k) {
          unsigned p = Hb[(size_t)m[k].x * 64 + lane];
          lo[k] = __uint_as_float(p << 16);
          hi[k] = __uint_as_float(p & 0xFFFF0000u);
        }
#pragma unroll
        for (int k = 0; k < 8; ++k) {
          float w = __uint_as_float(m[k].y);
          ax = fmaf(lo[k], w, ax);
          ay = fmaf(hi[k], w, ay);
        }
      }
      for (; j < s1; ++j) {
        uint2 m = sorted[j];
        float w = __uint_as_float(m.y);
        unsigned p = Hb[(size_t)m.x * 64 + lane];
        ax = fmaf(__uint_as_float(p << 16), w, ax);
        ay = fmaf(__uint_as_float(p & 0xFFFF0000u), w, ay);
      }
      unsigned pack = (unsigned)f32_to_bf16_rne(ax) |
                      ((unsigned)f32_to_bf16_rne(ay) << 16);
      hb_out[(size_t)node * 64 + lane] = pack;
    }
  } else {
    // Pathological bucket (>CAP2 edges): filter-scan, correct but slow.
#pragma unroll
    for (int i = 0; i < 4; ++i) {
      int dl = wid * 4 + i;
      int node = (bk << BKSH) + dl;
      if (node >= N) break;
      float ax = 0.0f, ay = 0.0f;
      for (int j = base; j < end; ++j) {
        uint2 m = payload[j];
        if ((int)(m.x >> 17) == dl) {
          float w = __uint_as_float(m.y);
          unsigned p = Hb[(size_t)(m.x & 0x1FFFFu) * 64 + lane];
          ax = fmaf(__uint_as_float(p << 16), w, ax);
          ay = fmaf(__uint_as_float(p & 0xFFFF0000u), w, ay);
        }
      }
      unsigned pack = (unsigned)f32_to_bf16_rne(ax) |
                      ((unsigned)f32_to_bf16_rne(ay) << 16);
      hb_out[(size_t)node * 64 + lane] = pack;
    }
  }
}

// ---------------- MFMA GEMM + GELU (BN pre-folded, round-9 verified) -------
__global__ __launch_bounds__(256) void mfma_gemm_gelu_kernel(
    const unsigned short* __restrict__ hb,      // [N][128] bf16
    const unsigned short* __restrict__ W2frag,  // fragment-ordered bf16
    const float* __restrict__ bias2,            // [128]
    float* __restrict__ out, int N) {
  __shared__ unsigned short sW[8 * 4 * 64 * 8];  // 32 KB

  int t = threadIdx.x;
  {
    const uint4* src = (const uint4*)W2frag;
    uint4* dst = (uint4*)sW;
    for (int i = t; i < 2048; i += 256) dst[i] = src[i];
  }
  __syncthreads();

  int wid = t >> 6;
  int l = t & 63;
  int row0 = blockIdx.x * 64 + wid * 16;

  int arow = row0 + (l & 15);
  if (arow >= N) arow = N - 1;  // clamp (stores guarded)
  const short8* hrow = (const short8*)(hb + (size_t)arow * DF);
  int asub = l >> 4;
  short8 a[4];
#pragma unroll
  for (int kt = 0; kt < 4; ++kt) a[kt] = hrow[kt * 4 + asub];

  const short8* wf = (const short8*)sW;
  int orow = (l >> 4) * 4;  // C/D: row=(lane>>4)*4+reg, col=lane&15 (m89)
  int ocol = l & 15;

#pragma unroll
  for (int ct = 0; ct < 8; ++ct) {
    f32x4 acc = {0.0f, 0.0f, 0.0f, 0.0f};
#pragma unroll
    for (int kt = 0; kt < 4; ++kt) {
      short8 bfr = wf[(ct * 4 + kt) * 64 + l];
      acc = __builtin_amdgcn_mfma_f32_16x16x32_bf16(a[kt], bfr, acc, 0, 0, 0);
    }
    int col = ct * 16 + ocol;
    float bb = bias2[col];
#pragma unroll
    for (int r = 0; r < 4; ++r) {
      int row = row0 + orow + r;
      if (row < N) {
        float x = acc[r] + bb;
        float g = 0.5f * x * (1.0f + erff(x * 0.70710678118654752440f));
        out[(size_t)row * DF + col] = g;
      }
    }
  }
}

// ---------------- tier-B kernels (round-8 verified) ----------------
__global__ __launch_bounds__(256) void reorder2_kernel(
    const uint2* __restrict__ payload, const int* __restrict__ gbase,
    uint2* __restrict__ csr, int* __restrict__ rowptr,
    int N, int nbk, int E) {
  __shared__ uint2 stage[CAP];
  __shared__ int cnt[BKNODES];
  __shared__ int s64[BKNODES];
  __shared__ int cur[BKNODES];
  int bk = blockIdx.x;
  int t = threadIdx.x;
  int base = gbase[(size_t)bk * NB];
  int end  = gbase[(size_t)(bk + 1) * NB];
  int len = end - base;
  bool fit = (len <= CAP);

  if (t < BKNODES) cnt[t] = 0;
  __syncthreads();
  if (fit) {
    for (int j = t; j < len; j += 256) {
      uint2 m = payload[base + j];
      stage[j] = m;
      atomicAdd(&cnt[m.x >> 17], 1);
    }
  } else {
    for (int j = t; j < len; j += 256)
      atomicAdd(&cnt[payload[base + j].x >> 17], 1);
  }
  __syncthreads();
  if (t < BKNODES) s64[t] = cnt[t];
  __syncthreads();
  for (int off = 1; off < BKNODES; off <<= 1) {
    int tmp = 0;
    if (t < BKNODES && t >= off) tmp = s64[t - off];
    __syncthreads();
    if (t < BKNODES) s64[t] += tmp;
    __syncthreads();
  }
  if (t < BKNODES) {
    int ex = s64[t] - cnt[t];
    cur[t] = ex;
    int node = (bk << BKSH) + t;
    if (node < N) rowptr[node] = base + ex;
  }
  if (bk == nbk - 1 && t == 0) rowptr[N] = E;
  __syncthreads();
  if (fit) {
    for (int j = t; j < len; j += 256) {
      uint2 m = stage[j];
      int dl = (int)(m.x >> 17);
      int pos = atomicAdd(&cur[dl], 1);
      uint2 o;
      o.x = m.x & 0x1FFFFu;
      o.y = m.y;
      csr[(size_t)base + pos] = o;
    }
  } else {
    for (int j = t; j < len; j += 256) {
      uint2 m = payload[base + j];
      int dl = (int)(m.x >> 17);
      int pos = atomicAdd(&cur[dl], 1);
      uint2 o;
      o.x = m.x & 0x1FFFFu;
      o.y = m.y;
      csr[(size_t)base + pos] = o;
    }
  }
}

__global__ __launch_bounds__(256) void pull_csr_f32_kernel(
    const float2* __restrict__ H2, const int* __restrict__ rowptr,
    const uint2* __restrict__ csr_sw, float* __restrict__ h, int N) {
  int wave = threadIdx.x >> 6;
  int lane = threadIdx.x & 63;
  int node = blockIdx.x * 4 + wave;
  if (node >= N) return;
  int rs = rowptr[node];
  int re = rowptr[node + 1];
  float ax = 0.0f, ay = 0.0f;
  for (int j = rs; j < re; ++j) {
    uint2 m = csr_sw[j];
    float w = __uint_as_float(m.y);
    float2 u = H2[(size_t)m.x * 64 + lane];
    ax = fmaf(u.x, w, ax);
    ay = fmaf(u.y, w, ay);
  }
  float2 r;
  r.x = ax;
  r.y = ay;
  reinterpret_cast<float2*>(h)[(size_t)node * 64 + lane] = r;
}

__global__ __launch_bounds__(256) void fused_bn_gemm_gelu(
    float* __restrict__ hout, const float* __restrict__ gamma,
    const float* __restrict__ beta, const float* __restrict__ mean,
    const float* __restrict__ var, const float* __restrict__ W,
    const float* __restrict__ b, int N) {
  __shared__ float s_s[DF];
  __shared__ float s_t[DF];
  __shared__ float s_hb[16][DF];
  __shared__ float s_W[32][DF];

  int t = threadIdx.x;
  if (t < DF) {
    float sv = gamma[t] * rsqrtf(var[t] + 1e-3f);
    s_s[t] = sv;
    s_t[t] = beta[t] - mean[t] * sv;
  }
  __syncthreads();

  int n0 = blockIdx.x * 16;
  for (int i = t; i < 16 * DF; i += 256) {
    int r = i >> 7;
    int c = i & (DF - 1);
    int node = n0 + r;
    float hv = (node < N) ? hout[(size_t)node * DF + c] : 0.0f;
    s_hb[r][c] = hv * s_s[c] + s_t[c];
  }

  float acc[8];
#pragma unroll
  for (int i = 0; i < 8; i++) acc[i] = 0.0f;

  int col = t & (DF - 1);
  int half = t >> 7;

  for (int kc = 0; kc < DF; kc += 32) {
    __syncthreads();
    for (int i = t; i < 32 * DF; i += 256) {
      int r = i >> 7;
      int c = i & (DF - 1);
      s_W[r][c] = W[(size_t)(kc + r) * DF + c];
    }
    __syncthreads();
#pragma unroll
    for (int kk = 0; kk < 32; kk++) {
      float wv = s_W[kk][col];
#pragma unroll
      for (int i = 0; i < 8; i++) {
        acc[i] += s_hb[half + i * 2][kc + kk] * wv;
      }
    }
  }

  float bb = b[col];
#pragma unroll
  for (int i = 0; i < 8; i++) {
    int node = n0 + half + i * 2;
    if (node < N) {
      float x = acc[i] + bb;
      float g = 0.5f * x * (1.0f + erff(x * 0.70710678118654752440f));
      hout[(size_t)node * DF + col] = g;
    }
  }
}

extern "C" void kernel_launch(void* const* d_in, const int* in_sizes, int n_in,
                              void* d_out, int out_size, void* d_ws, size_t ws_size,
                              hipStream_t stream) {
  const float* H     = (const float*)d_in[0];
  const int*   esrc  = (const int*)d_in[1];
  const int*   edst  = (const int*)d_in[2];
  const float* ew    = (const float*)d_in[3];
  const float* gamma = (const float*)d_in[4];
  const float* beta  = (const float*)d_in[5];
  const float* mean  = (const float*)d_in[6];
  const float* var   = (const float*)d_in[7];
  const float* W     = (const float*)d_in[8];
  const float* b     = (const float*)d_in[9];

  int N = in_sizes[0] / DF;
  int E = in_sizes[1];
  float* h = (float*)d_out;

  int nbk = (N + BKNODES - 1) / BKNODES;
  int NBKG = nbk * NB;
  int nbA = (NBKG + SCAN_ELEMS - 1) / SCAN_ELEMS;
  int chunk = (E + NB - 1) / NB;

  size_t off = 0;
  auto alloc = [&](size_t bytes) {
    size_t o = off;
    off += (bytes + 255) & ~(size_t)255;
    return o;
  };
  size_t o_bcnt   = alloc((size_t)NBKG * 4);
  size_t o_gbase  = alloc((size_t)(NBKG + 1) * 4);
  size_t o_bsum   = alloc((size_t)(nbA + 1) * 4);
  size_t o_rowptr = alloc((size_t)(N + 1) * 4);
  size_t o_w2     = alloc((size_t)16384 * 2);
  size_t o_bias2  = alloc((size_t)DF * 4);
  size_t o_pl     = alloc((size_t)E * 8);
  size_t o_csr    = alloc((size_t)E * 8);   // tier A: reused as bf16 h out
  size_t need_bin = off;
  size_t o_hb     = alloc((size_t)N * DF * 2);
  size_t need_bf16 = off;

  char* ws = (char*)d_ws;

  if (ws_size >= need_bin) {
    int* bcnt    = (int*)(ws + o_bcnt);
    int* gbase   = (int*)(ws + o_gbase);
    int* bsum    = (int*)(ws + o_bsum);
    int* rowptr  = (int*)(ws + o_rowptr);
    unsigned short* W2frag = (unsigned short*)(ws + o_w2);
    float* bias2 = (float*)(ws + o_bias2);
    uint2* payload = (uint2*)(ws + o_pl);
    uint2* csr     = (uint2*)(ws + o_csr);
    bool tierA = (ws_size >= need_bf16 && (size_t)N * DF * 2 <= (size_t)E * 8);

    size_t lds_bytes = (size_t)nbk * 4;

    if (tierA) {
      ushort4* Hb = (ushort4*)(ws + o_hb);
      int n4 = N * DF / 4;
      prep_all_kernel<<<(n4 + 255) / 256, 256, 0, stream>>>(
          (const float4*)H, Hb, n4, W, gamma, beta, mean, var, b, W2frag, bias2);
      hist_blk_kernel<<<NB, 512, lds_bytes, stream>>>(edst, bcnt, E, nbk, chunk);
      scan1_kernel<<<nbA, 256, 0, stream>>>(bcnt, gbase, bsum, NBKG);
      scan23_kernel<<<(NBKG + 255) / 256, 256, 0, stream>>>(gbase, bsum, NBKG, nbA);
      scatter_blk_kernel<<<NB, 512, lds_bytes, stream>>>(esrc, edst, ew, gbase,
                                                         payload, E, nbk, chunk);
      unsigned* hb_out = (unsigned*)(ws + o_csr);  // csr space reused
      reorder_pull_kernel<<<nbk, 1024, 0, stream>>>(
          (const unsigned*)Hb, payload, gbase, hb_out, N);
      mfma_gemm_gelu_kernel<<<(N + 63) / 64, 256, 0, stream>>>(
          (const unsigned short*)hb_out, W2frag, bias2, (float*)d_out, N);
    } else {
      hist_blk_kernel<<<NB, 512, lds_bytes, stream>>>(edst, bcnt, E, nbk, chunk);
      scan1_kernel<<<nbA, 256, 0, stream>>>(bcnt, gbase, bsum, NBKG);
      scan23_kernel<<<(NBKG + 255) / 256, 256, 0, stream>>>(gbase, bsum, NBKG, nbA);
      scatter_blk_kernel<<<NB, 512, lds_bytes, stream>>>(esrc, edst, ew, gbase,
                                                         payload, E, nbk, chunk);
      reorder2_kernel<<<nbk, 256, 0, stream>>>(payload, gbase, csr, rowptr,
                                               N, nbk, E);
      pull_csr_f32_kernel<<<(N + 3) / 4, 256, 0, stream>>>(
          (const float2*)H, rowptr, csr, h, N);
      fused_bn_gemm_gelu<<<(N + 15) / 16, 256, 0, stream>>>(h, gamma, beta,
                                                            mean, var, W, b, N);
    }
  } else {
    hipMemsetAsync(d_out, 0, (size_t)out_size * sizeof(float), stream);
    long long threads = (long long)E * 32;
    long long grid = (threads + 255) / 256;
    scatter_kernel<<<(int)grid, 256, 0, stream>>>(H, esrc, edst, ew, h, E);
    fused_bn_gemm_gelu<<<(N + 15) / 16, 256, 0, stream>>>(h, gamma, beta,
                                                          mean, var, W, b, N);
  }
}